// Round 1
// baseline (1092.064 us; speedup 1.0000x reference)
//
#include <hip/hip_runtime.h>
#include <cstdint>
#include <cstddef>

// Problem constants (match reference)
#define NN   20000   // nodes
#define LL   50      // seq len
#define IND  128     // input dim
#define HH   64      // hidden
#define FH   256     // 4*H
#define NHID 256     // hidden layer of conv1
#define NCLS 16      // classes
#define VV   32000   // vocab
#define EE   640000  // edges

__device__ __forceinline__ float sigmf(float x) {
  return 1.0f / (1.0f + __expf(-x));
}
// overflow-safe tanh
__device__ __forceinline__ float tanhf_fast(float x) {
  float ax = fabsf(x);
  float t = __expf(-2.0f * ax);
  float r = (1.0f - t) / (1.0f + t);
  return copysignf(r, x);
}

// ---------------------------------------------------------------------------
// Generic tiled fp32 GEMM: C[M][Nc] = A[M][K] @ B (+bias, opt bias2, opt relu)
// B_IS_NK: B stored row-major [Nc][K] (dot over B rows, i.e. C = A @ B^T)
// else:    B stored row-major [K][Nc]
// Tile 64x64, K-chunk 16, 256 threads, 4x4 micro-tile.
// ---------------------------------------------------------------------------
template <bool B_IS_NK, bool RELU, bool TWO_BIAS>
__global__ __launch_bounds__(256) void gemm_kernel(
    const float* __restrict__ A, const float* __restrict__ B,
    const float* __restrict__ bias1, const float* __restrict__ bias2,
    float* __restrict__ C, int M, int Ncols, int K) {
  __shared__ float As[64 * 17];
  __shared__ float Bs[16 * 68];
  const int tid = threadIdx.x;
  const int tx = tid & 15, ty = tid >> 4;
  const int m0 = blockIdx.y * 64, n0 = blockIdx.x * 64;

  float acc[4][4];
#pragma unroll
  for (int i = 0; i < 4; ++i)
#pragma unroll
    for (int j = 0; j < 4; ++j) acc[i][j] = 0.0f;

  for (int k0 = 0; k0 < K; k0 += 16) {
    // stage A tile 64x16
    {
      int row = tid >> 2, c4 = tid & 3;
      float4 v = make_float4(0.f, 0.f, 0.f, 0.f);
      if (m0 + row < M)
        v = *(const float4*)(A + (size_t)(m0 + row) * K + k0 + c4 * 4);
      As[row * 17 + c4 * 4 + 0] = v.x;
      As[row * 17 + c4 * 4 + 1] = v.y;
      As[row * 17 + c4 * 4 + 2] = v.z;
      As[row * 17 + c4 * 4 + 3] = v.w;
    }
    // stage B tile into Bs[k][n]
    if constexpr (B_IS_NK) {
      int n = tid >> 2, c4 = tid & 3;
      float4 v = *(const float4*)(B + (size_t)(n0 + n) * K + k0 + c4 * 4);
      Bs[(c4 * 4 + 0) * 68 + n] = v.x;
      Bs[(c4 * 4 + 1) * 68 + n] = v.y;
      Bs[(c4 * 4 + 2) * 68 + n] = v.z;
      Bs[(c4 * 4 + 3) * 68 + n] = v.w;
    } else {
      int k = tid >> 4, n4 = tid & 15;
      float4 v = *(const float4*)(B + (size_t)(k0 + k) * Ncols + n0 + n4 * 4);
      *(float4*)(Bs + k * 68 + n4 * 4) = v;
    }
    __syncthreads();
#pragma unroll
    for (int k = 0; k < 16; ++k) {
      float4 bv = *(const float4*)(Bs + k * 68 + tx * 4);
      float a0 = As[(ty * 4 + 0) * 17 + k];
      float a1 = As[(ty * 4 + 1) * 17 + k];
      float a2 = As[(ty * 4 + 2) * 17 + k];
      float a3 = As[(ty * 4 + 3) * 17 + k];
      acc[0][0] += a0 * bv.x; acc[0][1] += a0 * bv.y; acc[0][2] += a0 * bv.z; acc[0][3] += a0 * bv.w;
      acc[1][0] += a1 * bv.x; acc[1][1] += a1 * bv.y; acc[1][2] += a1 * bv.z; acc[1][3] += a1 * bv.w;
      acc[2][0] += a2 * bv.x; acc[2][1] += a2 * bv.y; acc[2][2] += a2 * bv.z; acc[2][3] += a2 * bv.w;
      acc[3][0] += a3 * bv.x; acc[3][1] += a3 * bv.y; acc[3][2] += a3 * bv.z; acc[3][3] += a3 * bv.w;
    }
    __syncthreads();
  }
#pragma unroll
  for (int i = 0; i < 4; ++i) {
    int m = m0 + ty * 4 + i;
    if (m >= M) continue;
#pragma unroll
    for (int j = 0; j < 4; ++j) {
      int n = n0 + tx * 4 + j;
      float v = acc[i][j] + bias1[n];
      if constexpr (TWO_BIAS) v += bias2[n];
      if constexpr (RELU) v = fmaxf(v, 0.0f);
      C[(size_t)m * Ncols + n] = v;
    }
  }
}

// ---------------------------------------------------------------------------
// LSTM over 50 steps. 32 nodes/block, 256 threads = 64 d-lanes x 4 node-groups
// (8 nodes per thread). W_hh XOR-swizzled in LDS, h in LDS, c in registers.
// gates = embW[feat[n][t]] + h @ W_hh^T, torch gate order i,f,g,o.
// ---------------------------------------------------------------------------
__global__ __launch_bounds__(256, 2) void lstm_kernel(
    const int* __restrict__ feat, const float* __restrict__ embW,
    const float* __restrict__ W_hh, float* __restrict__ h_out) {
  extern __shared__ char smem[];
  float* W_lds = (float*)smem;                     // 256*64 floats, swizzled (64 KB)
  float* h_lds = (float*)(smem + 65536);           // 32*64 floats (8 KB)
  int*   f_lds = (int*)(smem + 65536 + 8192);      // 32*50 ints (6.4 KB)

  const int tid = threadIdx.x;
  const int d   = tid & 63;
  const int nt  = tid >> 6;         // 0..3, node group
  const int n0  = blockIdx.x * 32;  // global node base

  // init h = 0
  for (int i = tid; i < 32 * 64; i += 256) h_lds[i] = 0.0f;
  // stage W_hh swizzled: element (j, kb*4..) stored at kb' = kb ^ (j&15)
  for (int idx = tid; idx < 4096; idx += 256) {
    int j = idx >> 4, kb = idx & 15;
    float4 w = *(const float4*)(W_hh + j * 64 + kb * 4);
    *(float4*)(W_lds + j * 64 + ((kb ^ (j & 15)) << 2)) = w;
  }
  // stage this block's feature rows (contiguous region)
  for (int idx = tid; idx < 32 * LL; idx += 256)
    f_lds[idx] = feat[n0 * LL + idx];
  __syncthreads();

  float c_reg[8];
#pragma unroll
  for (int n = 0; n < 8; ++n) c_reg[n] = 0.0f;

  const int swd = d & 15;

  for (int t = 0; t < LL; ++t) {
    // issue embW gathers early (consumed at epilogue; latency hides under GEMM)
    float ew[8][4];
#pragma unroll
    for (int n = 0; n < 8; ++n) {
      int row = f_lds[(nt * 8 + n) * LL + t];
      const float* er = embW + (size_t)row * FH;
      ew[n][0] = er[d];
      ew[n][1] = er[64 + d];
      ew[n][2] = er[128 + d];
      ew[n][3] = er[192 + d];
    }
    float acc[8][4];
#pragma unroll
    for (int n = 0; n < 8; ++n)
#pragma unroll
      for (int g = 0; g < 4; ++g) acc[n][g] = 0.0f;

#pragma unroll 4
    for (int kb = 0; kb < 16; ++kb) {
      const int so = ((kb ^ swd) << 2);
      float4 wv0 = *(const float4*)(W_lds + (0 * 4096) + d * 64 + so);
      float4 wv1 = *(const float4*)(W_lds + (1 * 4096) + d * 64 + so);
      float4 wv2 = *(const float4*)(W_lds + (2 * 4096) + d * 64 + so);
      float4 wv3 = *(const float4*)(W_lds + (3 * 4096) + d * 64 + so);
#pragma unroll
      for (int n = 0; n < 8; ++n) {
        float4 hv = *(const float4*)(h_lds + (nt * 8 + n) * 64 + kb * 4);
        acc[n][0] += hv.x * wv0.x + hv.y * wv0.y + hv.z * wv0.z + hv.w * wv0.w;
        acc[n][1] += hv.x * wv1.x + hv.y * wv1.y + hv.z * wv1.z + hv.w * wv1.w;
        acc[n][2] += hv.x * wv2.x + hv.y * wv2.y + hv.z * wv2.z + hv.w * wv2.w;
        acc[n][3] += hv.x * wv3.x + hv.y * wv3.y + hv.z * wv3.z + hv.w * wv3.w;
      }
    }
    __syncthreads();  // all reads of old h done
#pragma unroll
    for (int n = 0; n < 8; ++n) {
      float gi = sigmf(acc[n][0] + ew[n][0]);
      float gf = sigmf(acc[n][1] + ew[n][1]);
      float gg = tanhf_fast(acc[n][2] + ew[n][2]);
      float go = sigmf(acc[n][3] + ew[n][3]);
      float c = gf * c_reg[n] + gi * gg;
      c_reg[n] = c;
      h_lds[(nt * 8 + n) * 64 + d] = go * tanhf_fast(c);
    }
    __syncthreads();  // new h visible
  }
#pragma unroll
  for (int n = 0; n < 8; ++n)
    h_out[(size_t)(n0 + nt * 8 + n) * HH + d] = h_lds[(nt * 8 + n) * 64 + d];
}

// ---------------------------------------------------------------------------
// Graph plumbing
// ---------------------------------------------------------------------------
__global__ __launch_bounds__(256) void deg_kernel(
    const int* __restrict__ src, const int* __restrict__ dst,
    int* __restrict__ deg_out, int* __restrict__ deg_in) {
  int i = blockIdx.x * 256 + threadIdx.x;
  if (i < EE) {
    atomicAdd(&deg_out[src[i]], 1);
    atomicAdd(&deg_in[dst[i]], 1);
  }
}

// single-block exclusive scan of deg_in[NN] -> row_off[NN+1]
__global__ __launch_bounds__(1024) void scan_kernel(
    const int* __restrict__ deg_in, int* __restrict__ row_off) {
  __shared__ int partial[1024];
  const int tid = threadIdx.x;
  constexpr int CH = 20;  // 1024*20 >= 20000
  int base = tid * CH;
  int local[CH];
  int s = 0;
#pragma unroll
  for (int i = 0; i < CH; ++i) {
    int v = (base + i < NN) ? deg_in[base + i] : 0;
    local[i] = s;  // exclusive within chunk
    s += v;
  }
  partial[tid] = s;
  __syncthreads();
  for (int off = 1; off < 1024; off <<= 1) {
    int v = (tid >= off) ? partial[tid - off] : 0;
    __syncthreads();
    partial[tid] += v;
    __syncthreads();
  }
  int pre = (tid > 0) ? partial[tid - 1] : 0;
#pragma unroll
  for (int i = 0; i < CH; ++i)
    if (base + i < NN) row_off[base + i] = pre + local[i];
  if (tid == 1023) row_off[NN] = partial[1023];
}

__global__ __launch_bounds__(256) void norm_kernel(
    const int* __restrict__ deg_out, const int* __restrict__ deg_in,
    float* __restrict__ n_src, float* __restrict__ n_dst) {
  int i = blockIdx.x * 256 + threadIdx.x;
  if (i >= NN) return;
  int dro = deg_out[i], dri = deg_in[i];
  n_src[i] = (dro > 0) ? 1.0f / sqrtf((float)dro) : 1.0f;
  n_dst[i] = (dri > 0) ? 1.0f / sqrtf((float)dri) : 1.0f;
}

__global__ __launch_bounds__(256) void fill_kernel(
    const int* __restrict__ src, const int* __restrict__ dst,
    const int* __restrict__ row_off, int* __restrict__ cursor,
    int* __restrict__ csr_src) {
  int i = blockIdx.x * 256 + threadIdx.x;
  if (i < EE) {
    int d = dst[i];
    int pos = atomicAdd(&cursor[d], 1);
    csr_src[row_off[d] + pos] = src[i];
  }
}

// conv1 aggregation: agg[n][0:64] = n_dst[n] * sum_{s->n} h[s]*n_src[s]
// one wave per node, lane = dim
__global__ __launch_bounds__(256) void agg1_kernel(
    const float* __restrict__ h, const int* __restrict__ csr,
    const int* __restrict__ roff, const float* __restrict__ nsrc,
    const float* __restrict__ ndst, float* __restrict__ agg) {
  int node = blockIdx.x * 4 + (threadIdx.x >> 6);
  int lane = threadIdx.x & 63;
  if (node >= NN) return;
  int beg = roff[node], end = roff[node + 1];
  float a = 0.0f;
  int e = beg;
  for (; e + 4 <= end; e += 4) {
    int s0 = csr[e], s1 = csr[e + 1], s2 = csr[e + 2], s3 = csr[e + 3];
    float w0 = nsrc[s0], w1 = nsrc[s1], w2 = nsrc[s2], w3 = nsrc[s3];
    a += h[(size_t)s0 * HH + lane] * w0;
    a += h[(size_t)s1 * HH + lane] * w1;
    a += h[(size_t)s2 * HH + lane] * w2;
    a += h[(size_t)s3 * HH + lane] * w3;
  }
  for (; e < end; ++e) {
    int s = csr[e];
    a += h[(size_t)s * HH + lane] * nsrc[s];
  }
  agg[(size_t)node * HH + lane] = a * ndst[node];
}

// z = out1 @ W2  ([NN,256] @ [256,16]) — no bias (added after aggregation)
__global__ __launch_bounds__(256) void gemm16_kernel(
    const float* __restrict__ A, const float* __restrict__ W2,
    float* __restrict__ z) {
  __shared__ float w[NHID * NCLS];  // [k][j], 16 KB
  for (int i = threadIdx.x; i < NHID * NCLS; i += 256) w[i] = W2[i];
  __syncthreads();
  int node = blockIdx.x * 16 + (threadIdx.x >> 4);
  int j = threadIdx.x & 15;
  if (node >= NN) return;
  const float* a = A + (size_t)node * NHID;
  float acc = 0.0f;
#pragma unroll 8
  for (int k = 0; k < NHID; k += 4) {
    float4 av = *(const float4*)(a + k);
    acc += av.x * w[(k + 0) * NCLS + j] + av.y * w[(k + 1) * NCLS + j] +
           av.z * w[(k + 2) * NCLS + j] + av.w * w[(k + 3) * NCLS + j];
  }
  z[(size_t)node * NCLS + j] = acc;
}

// conv2 final aggregation: out[n][j] = n_dst[n]*sum_{s->n} z[s][j]*n_src[s] + b2[j]
// wave per node: 4 parallel edges x 16 dims
__global__ __launch_bounds__(256) void agg2_kernel(
    const float* __restrict__ z, const int* __restrict__ csr,
    const int* __restrict__ roff, const float* __restrict__ nsrc,
    const float* __restrict__ ndst, const float* __restrict__ b2,
    float* __restrict__ out) {
  int node = blockIdx.x * 4 + (threadIdx.x >> 6);
  int lane = threadIdx.x & 63;
  if (node >= NN) return;
  int dim = lane & 15, es = lane >> 4;
  int beg = roff[node], end = roff[node + 1];
  float a = 0.0f;
  for (int e = beg + es; e < end; e += 4) {
    int s = csr[e];
    a += z[(size_t)s * NCLS + dim] * nsrc[s];
  }
  a += __shfl_xor(a, 16, 64);
  a += __shfl_xor(a, 32, 64);
  if (lane < 16) out[(size_t)node * NCLS + dim] = ndst[node] * a + b2[dim];
}

// ---------------------------------------------------------------------------
extern "C" void kernel_launch(void* const* d_in, const int* in_sizes, int n_in,
                              void* d_out, int out_size, void* d_ws,
                              size_t ws_size, hipStream_t stream) {
  const int*   features = (const int*)d_in[0];
  const int*   src      = (const int*)d_in[1];
  const int*   dst      = (const int*)d_in[2];
  const float* emb      = (const float*)d_in[3];
  const float* W_ih     = (const float*)d_in[4];
  const float* W_hh     = (const float*)d_in[5];
  const float* b_ih     = (const float*)d_in[6];
  const float* b_hh     = (const float*)d_in[7];
  const float* W1       = (const float*)d_in[8];
  const float* b1       = (const float*)d_in[9];
  const float* W2       = (const float*)d_in[10];
  const float* b2       = (const float*)d_in[11];
  float* outp = (float*)d_out;

  // workspace layout (bytes). embW region is reused post-LSTM for agg/out1/z.
  char* ws = (char*)d_ws;
  float* embW    = (float*)(ws + 0);          // 32,768,000
  float* agg     = (float*)(ws + 0);          // 5,120,000 (alias, post-LSTM)
  float* out1    = (float*)(ws + 5120000);    // 20,480,000 (alias)
  float* z       = (float*)(ws + 25600000);   // 1,280,000 (alias)
  float* h       = (float*)(ws + 32768000);   // 5,120,000
  int*   deg_out = (int*)(ws + 37888000);     // 80,000
  int*   deg_in  = (int*)(ws + 37968000);     // 80,000
  int*   cursor  = (int*)(ws + 38048000);     // 80,000
  int*   row_off = (int*)(ws + 38128000);     // 80,016 (20001 ints)
  float* n_src   = (float*)(ws + 38208016);   // 80,000
  float* n_dst   = (float*)(ws + 38288016);   // 80,000
  int*   csr     = (int*)(ws + 38368016);     // 2,560,000  -> end 40,928,016

  // zero the atomic counters (deg_out, deg_in, cursor are contiguous)
  hipMemsetAsync(ws + 37888000, 0, 240000, stream);

  // allow 80,128 B dynamic LDS for the LSTM kernel
  hipFuncSetAttribute((const void*)lstm_kernel,
                      hipFuncAttributeMaxDynamicSharedMemorySize, 80128);

  // embW = emb @ W_ih^T + b_ih + b_hh   [32000 x 256]
  gemm_kernel<true, false, true><<<dim3(4, 500), 256, 0, stream>>>(
      emb, W_ih, b_ih, b_hh, embW, VV, FH, IND);

  // LSTM -> final hidden h [20000 x 64]
  lstm_kernel<<<625, 256, 80128, stream>>>(features, embW, W_hh, h);

  // graph degrees / CSR
  deg_kernel<<<2500, 256, 0, stream>>>(src, dst, deg_out, deg_in);
  scan_kernel<<<1, 1024, 0, stream>>>(deg_in, row_off);
  norm_kernel<<<79, 256, 0, stream>>>(deg_out, deg_in, n_src, n_dst);
  fill_kernel<<<2500, 256, 0, stream>>>(src, dst, row_off, cursor, csr);

  // conv1: aggregate then linear+relu
  agg1_kernel<<<5000, 256, 0, stream>>>(h, csr, row_off, n_src, n_dst, agg);
  gemm_kernel<false, true, false><<<dim3(4, 313), 256, 0, stream>>>(
      agg, W1, b1, nullptr, out1, NN, NHID, HH);

  // conv2: push W2 through the (linear) aggregation: z = out1 @ W2, then aggregate 16-wide
  gemm16_kernel<<<1250, 256, 0, stream>>>(out1, W2, z);
  agg2_kernel<<<5000, 256, 0, stream>>>(z, csr, row_off, n_src, n_dst, b2, outp);
}

// Round 3
// 611.348 us; speedup vs baseline: 1.7863x; 1.7863x over previous
//
#include <hip/hip_runtime.h>
#include <cstdint>
#include <cstddef>

// Problem constants (match reference)
#define NN   20000   // nodes
#define LL   50      // seq len
#define IND  128     // input dim
#define HH   64      // hidden
#define FH   256     // 4*H
#define NHID 256     // hidden layer of conv1
#define NCLS 16      // classes
#define VV   32000   // vocab
#define EE   640000  // edges

typedef _Float16 f16x8 __attribute__((ext_vector_type(8)));
typedef float    f32x4 __attribute__((ext_vector_type(4)));

__device__ __forceinline__ float sigmf(float x) {
  return 1.0f / (1.0f + __expf(-x));
}
// overflow-safe tanh
__device__ __forceinline__ float tanhf_fast(float x) {
  float ax = fabsf(x);
  float t = __expf(-2.0f * ax);
  float r = (1.0f - t) / (1.0f + t);
  return copysignf(r, x);
}

// ---------------------------------------------------------------------------
// Generic tiled fp32 GEMM: C[M][Nc] = A[M][K] @ B (+bias1 [+bias2] [relu])
// B_IS_NK: B stored row-major [Nc][K] (C = A @ B^T); else B is [K][Nc].
// PERM: store column j at permuted index (j&15)*16 + ((j>>4)&3)*4 + (j>>6)
//       (used for embW2 so the LSTM's per-(node,dt) gate quad is contiguous).
// ---------------------------------------------------------------------------
template <bool B_IS_NK, bool RELU, bool TWO_BIAS, bool PERM>
__global__ __launch_bounds__(256) void gemm_kernel(
    const float* __restrict__ A, const float* __restrict__ B,
    const float* __restrict__ bias1, const float* __restrict__ bias2,
    float* __restrict__ C, int M, int Ncols, int K) {
  __shared__ float As[64 * 17];
  __shared__ float Bs[16 * 68];
  const int tid = threadIdx.x;
  const int tx = tid & 15, ty = tid >> 4;
  const int m0 = blockIdx.y * 64, n0 = blockIdx.x * 64;

  float acc[4][4];
#pragma unroll
  for (int i = 0; i < 4; ++i)
#pragma unroll
    for (int j = 0; j < 4; ++j) acc[i][j] = 0.0f;

  for (int k0 = 0; k0 < K; k0 += 16) {
    {
      int row = tid >> 2, c4 = tid & 3;
      float4 v = make_float4(0.f, 0.f, 0.f, 0.f);
      if (m0 + row < M)
        v = *(const float4*)(A + (size_t)(m0 + row) * K + k0 + c4 * 4);
      As[row * 17 + c4 * 4 + 0] = v.x;
      As[row * 17 + c4 * 4 + 1] = v.y;
      As[row * 17 + c4 * 4 + 2] = v.z;
      As[row * 17 + c4 * 4 + 3] = v.w;
    }
    if constexpr (B_IS_NK) {
      int n = tid >> 2, c4 = tid & 3;
      float4 v = *(const float4*)(B + (size_t)(n0 + n) * K + k0 + c4 * 4);
      Bs[(c4 * 4 + 0) * 68 + n] = v.x;
      Bs[(c4 * 4 + 1) * 68 + n] = v.y;
      Bs[(c4 * 4 + 2) * 68 + n] = v.z;
      Bs[(c4 * 4 + 3) * 68 + n] = v.w;
    } else {
      int k = tid >> 4, n4 = tid & 15;
      float4 v = *(const float4*)(B + (size_t)(k0 + k) * Ncols + n0 + n4 * 4);
      *(float4*)(Bs + k * 68 + n4 * 4) = v;
    }
    __syncthreads();
#pragma unroll
    for (int k = 0; k < 16; ++k) {
      float4 bv = *(const float4*)(Bs + k * 68 + tx * 4);
      float a0 = As[(ty * 4 + 0) * 17 + k];
      float a1 = As[(ty * 4 + 1) * 17 + k];
      float a2 = As[(ty * 4 + 2) * 17 + k];
      float a3 = As[(ty * 4 + 3) * 17 + k];
      acc[0][0] += a0 * bv.x; acc[0][1] += a0 * bv.y; acc[0][2] += a0 * bv.z; acc[0][3] += a0 * bv.w;
      acc[1][0] += a1 * bv.x; acc[1][1] += a1 * bv.y; acc[1][2] += a1 * bv.z; acc[1][3] += a1 * bv.w;
      acc[2][0] += a2 * bv.x; acc[2][1] += a2 * bv.y; acc[2][2] += a2 * bv.z; acc[2][3] += a2 * bv.w;
      acc[3][0] += a3 * bv.x; acc[3][1] += a3 * bv.y; acc[3][2] += a3 * bv.z; acc[3][3] += a3 * bv.w;
    }
    __syncthreads();
  }
#pragma unroll
  for (int i = 0; i < 4; ++i) {
    int m = m0 + ty * 4 + i;
    if (m >= M) continue;
#pragma unroll
    for (int j = 0; j < 4; ++j) {
      int n = n0 + tx * 4 + j;
      float v = acc[i][j] + bias1[n];
      if constexpr (TWO_BIAS) v += bias2[n];
      if constexpr (RELU) v = fmaxf(v, 0.0f);
      int nn = PERM ? ((n & 15) * 16 + ((n >> 4) & 3) * 4 + (n >> 6)) : n;
      C[(size_t)m * Ncols + nn] = v;
    }
  }
}

// ---------------------------------------------------------------------------
// MFMA LSTM: 1250 blocks x 1 wave (64 threads), 16 nodes/block, 50 steps.
// gates[16x256] = h[16x64](f16) @ W_hh^T(f16, in 32 B-frags = 128 VGPR)
// via mfma_f32_16x16x32_f16; fp32 accumulate + fp32 c/activations.
// D-layout (col=lane&15, row=(lane>>4)*4+reg) puts all 4 gates of each (n,d)
// in the same lane -> activation is register-local, no cross-lane traffic.
// embW2 rows are gathered with a one-dt-slice-ahead software pipeline.
// h round-trips via a 2KB XOR-swizzled LDS fp16 buffer (block = d8 ^ (n&7)).
// ---------------------------------------------------------------------------
__global__ __launch_bounds__(64, 2) void lstm_mfma_kernel(
    const int* __restrict__ feat, const float* __restrict__ embW2,
    const float* __restrict__ W_hh, float* __restrict__ h_out) {
  __shared__ __align__(16) _Float16 hbuf[16 * 64];
  __shared__ int fbuf[16 * LL];

  const int l  = threadIdx.x;
  const int cc = l & 15;   // col-in-tile; also node index for A-frag reads
  const int g4 = l >> 4;   // 0..3
  const int n0 = blockIdx.x * 16;

  // ---- W^T B-fragments in registers (fp32 -> fp16), 16 col-tiles x 2 k-halves
  f16x8 Bf[16][2];
#pragma unroll
  for (int ct = 0; ct < 16; ++ct)
#pragma unroll
    for (int kh = 0; kh < 2; ++kh) {
      const float* wp = W_hh + (ct * 16 + cc) * 64 + kh * 32 + g4 * 8;
      float4 w0 = *(const float4*)(wp);
      float4 w1 = *(const float4*)(wp + 4);
      f16x8 b;
      b[0] = (_Float16)w0.x; b[1] = (_Float16)w0.y;
      b[2] = (_Float16)w0.z; b[3] = (_Float16)w0.w;
      b[4] = (_Float16)w1.x; b[5] = (_Float16)w1.y;
      b[6] = (_Float16)w1.z; b[7] = (_Float16)w1.w;
      Bf[ct][kh] = b;
    }

  // ---- init h = 0 (fp16), stage this block's feature rows
  for (int i = l; i < 16 * 64; i += 64) hbuf[i] = (_Float16)0.0f;
  for (int i = l; i < 16 * LL; i += 64) fbuf[i] = feat[n0 * LL + i];

  // ---- A-frag LDS byte addresses (swizzled), loop-invariant
  const char* hb = (const char*)hbuf;
  const int aoff = cc * 128;
  const int sb0  = ((g4    ) ^ (cc & 7)) << 4;
  const int sb1  = ((g4 + 4) ^ (cc & 7)) << 4;

  float c_reg[16];
#pragma unroll
  for (int i = 0; i < 16; ++i) c_reg[i] = 0.0f;

  // ---- prologue of the embW gather pipeline (t=0, dt=0)
  int rr[4];
#pragma unroll
  for (int r = 0; r < 4; ++r) rr[r] = fbuf[(g4 * 4 + r) * LL + 0];
  float4 ewA[4];
#pragma unroll
  for (int r = 0; r < 4; ++r)
    ewA[r] = *(const float4*)(embW2 + (size_t)rr[r] * FH + cc * 16 + 0);

  for (int t = 0; t < LL; ++t) {
    // h(t-1) A-fragments (zeros at t=0)
    f16x8 A0 = *(const f16x8*)(hb + aoff + sb0);
    f16x8 A1 = *(const f16x8*)(hb + aoff + sb1);

    const int tn = (t < LL - 1) ? t + 1 : LL - 1;
    int rr2[4];
#pragma unroll
    for (int r = 0; r < 4; ++r) rr2[r] = fbuf[(g4 * 4 + r) * LL + tn];

#pragma unroll
    for (int dt = 0; dt < 4; ++dt) {
      f32x4 z = {0.f, 0.f, 0.f, 0.f};
      f32x4 aci = __builtin_amdgcn_mfma_f32_16x16x32_f16(A0, Bf[dt][0], z, 0, 0, 0);
      aci = __builtin_amdgcn_mfma_f32_16x16x32_f16(A1, Bf[dt][1], aci, 0, 0, 0);
      f32x4 acf = __builtin_amdgcn_mfma_f32_16x16x32_f16(A0, Bf[4 + dt][0], z, 0, 0, 0);
      acf = __builtin_amdgcn_mfma_f32_16x16x32_f16(A1, Bf[4 + dt][1], acf, 0, 0, 0);
      f32x4 acg = __builtin_amdgcn_mfma_f32_16x16x32_f16(A0, Bf[8 + dt][0], z, 0, 0, 0);
      acg = __builtin_amdgcn_mfma_f32_16x16x32_f16(A1, Bf[8 + dt][1], acg, 0, 0, 0);
      f32x4 aco = __builtin_amdgcn_mfma_f32_16x16x32_f16(A0, Bf[12 + dt][0], z, 0, 0, 0);
      aco = __builtin_amdgcn_mfma_f32_16x16x32_f16(A1, Bf[12 + dt][1], aco, 0, 0, 0);

      // issue next ew slice (one dt ahead; dt==3 issues next step's dt=0)
      float4 ewN[4];
      if (dt < 3) {
#pragma unroll
        for (int r = 0; r < 4; ++r)
          ewN[r] = *(const float4*)(embW2 + (size_t)rr[r] * FH + cc * 16 + (dt + 1) * 4);
      } else {
#pragma unroll
        for (int r = 0; r < 4; ++r)
          ewN[r] = *(const float4*)(embW2 + (size_t)rr2[r] * FH + cc * 16 + 0);
      }

      // activation (register-local; acc component r = node g4*4+r)
#pragma unroll
      for (int r = 0; r < 4; ++r) {
        float gi = sigmf(aci[r] + ewA[r].x);
        float gf = sigmf(acf[r] + ewA[r].y);
        float gg = tanhf_fast(acg[r] + ewA[r].z);
        float go = sigmf(aco[r] + ewA[r].w);
        float cn = gf * c_reg[dt * 4 + r] + gi * gg;
        c_reg[dt * 4 + r] = cn;
        float hn = go * tanhf_fast(cn);
        const int n = g4 * 4 + r;
        const int d = cc + 16 * dt;
        hbuf[n * 64 + ((((d >> 3)) ^ (n & 7)) << 3) + (d & 7)] = (_Float16)hn;
        if (t == LL - 1)
          h_out[(size_t)(n0 + n) * HH + d] = hn;
      }
#pragma unroll
      for (int r = 0; r < 4; ++r) ewA[r] = ewN[r];
    }
#pragma unroll
    for (int r = 0; r < 4; ++r) rr[r] = rr2[r];
  }
}

// ---------------------------------------------------------------------------
// Graph plumbing (unchanged from passing round)
// ---------------------------------------------------------------------------
__global__ __launch_bounds__(256) void deg_kernel(
    const int* __restrict__ src, const int* __restrict__ dst,
    int* __restrict__ deg_out, int* __restrict__ deg_in) {
  int i = blockIdx.x * 256 + threadIdx.x;
  if (i < EE) {
    atomicAdd(&deg_out[src[i]], 1);
    atomicAdd(&deg_in[dst[i]], 1);
  }
}

__global__ __launch_bounds__(1024) void scan_kernel(
    const int* __restrict__ deg_in, int* __restrict__ row_off) {
  __shared__ int partial[1024];
  const int tid = threadIdx.x;
  constexpr int CH = 20;
  int base = tid * CH;
  int local[CH];
  int s = 0;
#pragma unroll
  for (int i = 0; i < CH; ++i) {
    int v = (base + i < NN) ? deg_in[base + i] : 0;
    local[i] = s;
    s += v;
  }
  partial[tid] = s;
  __syncthreads();
  for (int off = 1; off < 1024; off <<= 1) {
    int v = (tid >= off) ? partial[tid - off] : 0;
    __syncthreads();
    partial[tid] += v;
    __syncthreads();
  }
  int pre = (tid > 0) ? partial[tid - 1] : 0;
#pragma unroll
  for (int i = 0; i < CH; ++i)
    if (base + i < NN) row_off[base + i] = pre + local[i];
  if (tid == 1023) row_off[NN] = partial[1023];
}

__global__ __launch_bounds__(256) void norm_kernel(
    const int* __restrict__ deg_out, const int* __restrict__ deg_in,
    float* __restrict__ n_src, float* __restrict__ n_dst) {
  int i = blockIdx.x * 256 + threadIdx.x;
  if (i >= NN) return;
  int dro = deg_out[i], dri = deg_in[i];
  n_src[i] = (dro > 0) ? 1.0f / sqrtf((float)dro) : 1.0f;
  n_dst[i] = (dri > 0) ? 1.0f / sqrtf((float)dri) : 1.0f;
}

__global__ __launch_bounds__(256) void fill_kernel(
    const int* __restrict__ src, const int* __restrict__ dst,
    const int* __restrict__ row_off, int* __restrict__ cursor,
    int* __restrict__ csr_src) {
  int i = blockIdx.x * 256 + threadIdx.x;
  if (i < EE) {
    int d = dst[i];
    int pos = atomicAdd(&cursor[d], 1);
    csr_src[row_off[d] + pos] = src[i];
  }
}

__global__ __launch_bounds__(256) void agg1_kernel(
    const float* __restrict__ h, const int* __restrict__ csr,
    const int* __restrict__ roff, const float* __restrict__ nsrc,
    const float* __restrict__ ndst, float* __restrict__ agg) {
  int node = blockIdx.x * 4 + (threadIdx.x >> 6);
  int lane = threadIdx.x & 63;
  if (node >= NN) return;
  int beg = roff[node], end = roff[node + 1];
  float a = 0.0f;
  int e = beg;
  for (; e + 4 <= end; e += 4) {
    int s0 = csr[e], s1 = csr[e + 1], s2 = csr[e + 2], s3 = csr[e + 3];
    float w0 = nsrc[s0], w1 = nsrc[s1], w2 = nsrc[s2], w3 = nsrc[s3];
    a += h[(size_t)s0 * HH + lane] * w0;
    a += h[(size_t)s1 * HH + lane] * w1;
    a += h[(size_t)s2 * HH + lane] * w2;
    a += h[(size_t)s3 * HH + lane] * w3;
  }
  for (; e < end; ++e) {
    int s = csr[e];
    a += h[(size_t)s * HH + lane] * nsrc[s];
  }
  agg[(size_t)node * HH + lane] = a * ndst[node];
}

__global__ __launch_bounds__(256) void gemm16_kernel(
    const float* __restrict__ A, const float* __restrict__ W2,
    float* __restrict__ z) {
  __shared__ float w[NHID * NCLS];
  for (int i = threadIdx.x; i < NHID * NCLS; i += 256) w[i] = W2[i];
  __syncthreads();
  int node = blockIdx.x * 16 + (threadIdx.x >> 4);
  int j = threadIdx.x & 15;
  if (node >= NN) return;
  const float* a = A + (size_t)node * NHID;
  float acc = 0.0f;
#pragma unroll 8
  for (int k = 0; k < NHID; k += 4) {
    float4 av = *(const float4*)(a + k);
    acc += av.x * w[(k + 0) * NCLS + j] + av.y * w[(k + 1) * NCLS + j] +
           av.z * w[(k + 2) * NCLS + j] + av.w * w[(k + 3) * NCLS + j];
  }
  z[(size_t)node * NCLS + j] = acc;
}

__global__ __launch_bounds__(256) void agg2_kernel(
    const float* __restrict__ z, const int* __restrict__ csr,
    const int* __restrict__ roff, const float* __restrict__ nsrc,
    const float* __restrict__ ndst, const float* __restrict__ b2,
    float* __restrict__ out) {
  int node = blockIdx.x * 4 + (threadIdx.x >> 6);
  int lane = threadIdx.x & 63;
  if (node >= NN) return;
  int dim = lane & 15, es = lane >> 4;
  int beg = roff[node], end = roff[node + 1];
  float a = 0.0f;
  for (int e = beg + es; e < end; e += 4) {
    int s = csr[e];
    a += z[(size_t)s * NCLS + dim] * nsrc[s];
  }
  a += __shfl_xor(a, 16, 64);
  a += __shfl_xor(a, 32, 64);
  if (lane < 16) out[(size_t)node * NCLS + dim] = ndst[node] * a + b2[dim];
}

// ---------------------------------------------------------------------------
extern "C" void kernel_launch(void* const* d_in, const int* in_sizes, int n_in,
                              void* d_out, int out_size, void* d_ws,
                              size_t ws_size, hipStream_t stream) {
  const int*   features = (const int*)d_in[0];
  const int*   src      = (const int*)d_in[1];
  const int*   dst      = (const int*)d_in[2];
  const float* emb      = (const float*)d_in[3];
  const float* W_ih     = (const float*)d_in[4];
  const float* W_hh     = (const float*)d_in[5];
  const float* b_ih     = (const float*)d_in[6];
  const float* b_hh     = (const float*)d_in[7];
  const float* W1       = (const float*)d_in[8];
  const float* b1       = (const float*)d_in[9];
  const float* W2       = (const float*)d_in[10];
  const float* b2       = (const float*)d_in[11];
  float* outp = (float*)d_out;

  // workspace layout (bytes). embW2 region is reused post-LSTM for agg/out1/z.
  char* ws = (char*)d_ws;
  float* embW2   = (float*)(ws + 0);          // 32,768,000
  float* agg     = (float*)(ws + 0);          // alias, post-LSTM
  float* out1    = (float*)(ws + 5120000);    // alias
  float* z       = (float*)(ws + 25600000);   // alias
  float* h       = (float*)(ws + 32768000);   // 5,120,000
  int*   deg_out = (int*)(ws + 37888000);
  int*   deg_in  = (int*)(ws + 37968000);
  int*   cursor  = (int*)(ws + 38048000);
  int*   row_off = (int*)(ws + 38128000);
  float* n_src   = (float*)(ws + 38208016);
  float* n_dst   = (float*)(ws + 38288016);
  int*   csr     = (int*)(ws + 38368016);     // -> end 40,928,016

  hipMemsetAsync(ws + 37888000, 0, 240000, stream);

  // embW2 = perm(emb @ W_ih^T + b_ih + b_hh)   [32000 x 256]
  gemm_kernel<true, false, true, true><<<dim3(4, 500), 256, 0, stream>>>(
      emb, W_ih, b_ih, b_hh, embW2, VV, FH, IND);

  // MFMA LSTM -> final hidden h [20000 x 64]
  lstm_mfma_kernel<<<1250, 64, 0, stream>>>(features, embW2, W_hh, h);

  // graph degrees / CSR
  deg_kernel<<<2500, 256, 0, stream>>>(src, dst, deg_out, deg_in);
  scan_kernel<<<1, 1024, 0, stream>>>(deg_in, row_off);
  norm_kernel<<<79, 256, 0, stream>>>(deg_out, deg_in, n_src, n_dst);
  fill_kernel<<<2500, 256, 0, stream>>>(src, dst, row_off, cursor, csr);

  // conv1: aggregate then linear+relu
  agg1_kernel<<<5000, 256, 0, stream>>>(h, csr, row_off, n_src, n_dst, agg);
  gemm_kernel<false, true, false, false><<<dim3(4, 313), 256, 0, stream>>>(
      agg, W1, b1, nullptr, out1, NN, NHID, HH);

  // conv2: push W2 through the (linear) aggregation
  gemm16_kernel<<<1250, 256, 0, stream>>>(out1, W2, z);
  agg2_kernel<<<5000, 256, 0, stream>>>(z, csr, row_off, n_src, n_dst, b2, outp);
}

// Round 5
// 519.592 us; speedup vs baseline: 2.1018x; 1.1766x over previous
//
#include <hip/hip_runtime.h>
#include <cstdint>
#include <cstddef>

// Problem constants (match reference)
#define NN   20000   // nodes
#define LL   50      // seq len
#define IND  128     // input dim
#define HH   64      // hidden
#define FH   256     // 4*H
#define NHID 256     // hidden layer of conv1
#define NCLS 16      // classes
#define VV   32000   // vocab
#define EE   640000  // edges

typedef _Float16 f16x8 __attribute__((ext_vector_type(8)));
typedef float    f32x4 __attribute__((ext_vector_type(4)));

__device__ __forceinline__ float sigmf(float x) {
  return 1.0f / (1.0f + __expf(-x));
}
// overflow-safe tanh
__device__ __forceinline__ float tanhf_fast(float x) {
  float ax = fabsf(x);
  float t = __expf(-2.0f * ax);
  float r = (1.0f - t) / (1.0f + t);
  return copysignf(r, x);
}

// ---------------------------------------------------------------------------
// Generic tiled fp32 GEMM: C[M][Nc] = A[M][K] @ B (+bias1 [+bias2] [relu])
// B_IS_NK: B stored row-major [Nc][K] (C = A @ B^T); else B is [K][Nc].
// PERM: store column j at nn = ((j>>4)&3)*64 + (j&15)*4 + (j>>6)
//       (embW2 layout: [dt][cc][gate] -> per-(node,d) gate quad is one float4
//        AND 16 consecutive cc lanes read one contiguous 256B slice).
// ---------------------------------------------------------------------------
template <bool B_IS_NK, bool RELU, bool TWO_BIAS, bool PERM>
__global__ __launch_bounds__(256) void gemm_kernel(
    const float* __restrict__ A, const float* __restrict__ B,
    const float* __restrict__ bias1, const float* __restrict__ bias2,
    float* __restrict__ C, int M, int Ncols, int K) {
  __shared__ float As[64 * 17];
  __shared__ float Bs[16 * 68];
  const int tid = threadIdx.x;
  const int tx = tid & 15, ty = tid >> 4;
  const int m0 = blockIdx.y * 64, n0 = blockIdx.x * 64;

  float acc[4][4];
#pragma unroll
  for (int i = 0; i < 4; ++i)
#pragma unroll
    for (int j = 0; j < 4; ++j) acc[i][j] = 0.0f;

  for (int k0 = 0; k0 < K; k0 += 16) {
    {
      int row = tid >> 2, c4 = tid & 3;
      float4 v = make_float4(0.f, 0.f, 0.f, 0.f);
      if (m0 + row < M)
        v = *(const float4*)(A + (size_t)(m0 + row) * K + k0 + c4 * 4);
      As[row * 17 + c4 * 4 + 0] = v.x;
      As[row * 17 + c4 * 4 + 1] = v.y;
      As[row * 17 + c4 * 4 + 2] = v.z;
      As[row * 17 + c4 * 4 + 3] = v.w;
    }
    if constexpr (B_IS_NK) {
      int n = tid >> 2, c4 = tid & 3;
      float4 v = *(const float4*)(B + (size_t)(n0 + n) * K + k0 + c4 * 4);
      Bs[(c4 * 4 + 0) * 68 + n] = v.x;
      Bs[(c4 * 4 + 1) * 68 + n] = v.y;
      Bs[(c4 * 4 + 2) * 68 + n] = v.z;
      Bs[(c4 * 4 + 3) * 68 + n] = v.w;
    } else {
      int k = tid >> 4, n4 = tid & 15;
      float4 v = *(const float4*)(B + (size_t)(k0 + k) * Ncols + n0 + n4 * 4);
      *(float4*)(Bs + k * 68 + n4 * 4) = v;
    }
    __syncthreads();
#pragma unroll
    for (int k = 0; k < 16; ++k) {
      float4 bv = *(const float4*)(Bs + k * 68 + tx * 4);
      float a0 = As[(ty * 4 + 0) * 17 + k];
      float a1 = As[(ty * 4 + 1) * 17 + k];
      float a2 = As[(ty * 4 + 2) * 17 + k];
      float a3 = As[(ty * 4 + 3) * 17 + k];
      acc[0][0] += a0 * bv.x; acc[0][1] += a0 * bv.y; acc[0][2] += a0 * bv.z; acc[0][3] += a0 * bv.w;
      acc[1][0] += a1 * bv.x; acc[1][1] += a1 * bv.y; acc[1][2] += a1 * bv.z; acc[1][3] += a1 * bv.w;
      acc[2][0] += a2 * bv.x; acc[2][1] += a2 * bv.y; acc[2][2] += a2 * bv.z; acc[2][3] += a2 * bv.w;
      acc[3][0] += a3 * bv.x; acc[3][1] += a3 * bv.y; acc[3][2] += a3 * bv.z; acc[3][3] += a3 * bv.w;
    }
    __syncthreads();
  }
#pragma unroll
  for (int i = 0; i < 4; ++i) {
    int m = m0 + ty * 4 + i;
    if (m >= M) continue;
#pragma unroll
    for (int j = 0; j < 4; ++j) {
      int n = n0 + tx * 4 + j;
      float v = acc[i][j] + bias1[n];
      if constexpr (TWO_BIAS) v += bias2[n];
      if constexpr (RELU) v = fmaxf(v, 0.0f);
      int nn = PERM ? (((n >> 4) & 3) * 64 + (n & 15) * 4 + (n >> 6)) : n;
      C[(size_t)m * Ncols + nn] = v;
    }
  }
}

// ---------------------------------------------------------------------------
// MFMA LSTM, 4-wave d-split: 1250 blocks x 256 threads (4 waves), 16 nodes
// per block, wave w owns d in [16w, 16w+16) for all 16 nodes.
// Per wave per step: 8 mfma_f32_16x16x32_f16 (4 gates x 2 k-halves), 4
// activation quads/thread, 4 embW2 float4 gathers prefetched one full step
// ahead. h double-buffered in XOR-swizzled LDS (same fragment layout as the
// verified 1-wave kernel); one barrier per step.
// D-layout: row=(lane>>4)*4+reg -> node, col=lane&15 -> d-within-tile.
// ---------------------------------------------------------------------------
__global__ __launch_bounds__(256) void lstm_mfma4_kernel(
    const int* __restrict__ feat, const float* __restrict__ embW2,
    const float* __restrict__ W_hh, float* __restrict__ h_out) {
  __shared__ __align__(16) _Float16 hbuf[2][16 * 64];
  __shared__ int fbuf[16 * LL];

  const int tid = threadIdx.x;
  const int l   = tid & 63;
  const int w   = tid >> 6;   // wave id = d-tile (0..3)
  const int cc  = l & 15;
  const int g4  = l >> 4;
  const int n0  = blockIdx.x * 16;

  // ---- B-frags for this wave's 4 gate col-tiles (cols g*64 + w*16 + cc)
  f16x8 Bf[4][2];
#pragma unroll
  for (int g = 0; g < 4; ++g)
#pragma unroll
    for (int kh = 0; kh < 2; ++kh) {
      const float* wp = W_hh + (g * 64 + w * 16 + cc) * 64 + kh * 32 + g4 * 8;
      float4 w0 = *(const float4*)(wp);
      float4 w1 = *(const float4*)(wp + 4);
      f16x8 b;
      b[0] = (_Float16)w0.x; b[1] = (_Float16)w0.y;
      b[2] = (_Float16)w0.z; b[3] = (_Float16)w0.w;
      b[4] = (_Float16)w1.x; b[5] = (_Float16)w1.y;
      b[6] = (_Float16)w1.z; b[7] = (_Float16)w1.w;
      Bf[g][kh] = b;
    }

  // ---- zero both h buffers (h(-1)=0), stage feature rows
  for (int i = tid; i < 2 * 16 * 64; i += 256) ((_Float16*)hbuf)[i] = (_Float16)0.0f;
  for (int i = tid; i < 16 * LL; i += 256) fbuf[i] = feat[n0 * LL + i];

  // ---- A-frag read offsets (swizzled, same layout as verified kernel)
  const int aoff = cc * 128;
  const int sb0  = ((g4    ) ^ (cc & 7)) << 4;
  const int sb1  = ((g4 + 4) ^ (cc & 7)) << 4;

  // ---- h write byte-offsets: n = g4*4+r, d = w*16+cc
  int wr_off[4];
#pragma unroll
  for (int r = 0; r < 4; ++r) {
    int n = g4 * 4 + r;
    int dgrp = w * 2 + (cc >> 3);
    wr_off[r] = n * 128 + ((dgrp ^ (n & 7)) << 4) + (cc & 7) * 2;
  }

  float c_reg[4];
#pragma unroll
  for (int r = 0; r < 4; ++r) c_reg[r] = 0.0f;

  __syncthreads();

  // ---- prologue: ew for t=0
  float4 ewA[4];
#pragma unroll
  for (int r = 0; r < 4; ++r) {
    int row = fbuf[(g4 * 4 + r) * LL + 0];
    ewA[r] = *(const float4*)(embW2 + (size_t)row * FH + w * 64 + cc * 4);
  }

  for (int t = 0; t < LL; ++t) {
    const char* hbR = (const char*)hbuf[t & 1];        // h(t-1)
    _Float16*   hbW = hbuf[(t & 1) ^ 1];               // h(t)

    f16x8 A0 = *(const f16x8*)(hbR + aoff + sb0);
    f16x8 A1 = *(const f16x8*)(hbR + aoff + sb1);

    // issue next step's ew (full-step latency hiding)
    const int tn = (t < LL - 1) ? t + 1 : t;
    float4 ewN[4];
#pragma unroll
    for (int r = 0; r < 4; ++r) {
      int row = fbuf[(g4 * 4 + r) * LL + tn];
      ewN[r] = *(const float4*)(embW2 + (size_t)row * FH + w * 64 + cc * 4);
    }

    f32x4 z = {0.f, 0.f, 0.f, 0.f};
    f32x4 aci = __builtin_amdgcn_mfma_f32_16x16x32_f16(A0, Bf[0][0], z, 0, 0, 0);
    aci = __builtin_amdgcn_mfma_f32_16x16x32_f16(A1, Bf[0][1], aci, 0, 0, 0);
    f32x4 acf = __builtin_amdgcn_mfma_f32_16x16x32_f16(A0, Bf[1][0], z, 0, 0, 0);
    acf = __builtin_amdgcn_mfma_f32_16x16x32_f16(A1, Bf[1][1], acf, 0, 0, 0);
    f32x4 acg = __builtin_amdgcn_mfma_f32_16x16x32_f16(A0, Bf[2][0], z, 0, 0, 0);
    acg = __builtin_amdgcn_mfma_f32_16x16x32_f16(A1, Bf[2][1], acg, 0, 0, 0);
    f32x4 aco = __builtin_amdgcn_mfma_f32_16x16x32_f16(A0, Bf[3][0], z, 0, 0, 0);
    aco = __builtin_amdgcn_mfma_f32_16x16x32_f16(A1, Bf[3][1], aco, 0, 0, 0);

    // activation: acc component r -> node g4*4+r, at d = w*16+cc
#pragma unroll
    for (int r = 0; r < 4; ++r) {
      float gi = sigmf(aci[r] + ewA[r].x);
      float gf = sigmf(acf[r] + ewA[r].y);
      float gg = tanhf_fast(acg[r] + ewA[r].z);
      float go = sigmf(aco[r] + ewA[r].w);
      float cn = gf * c_reg[r] + gi * gg;
      c_reg[r] = cn;
      float hn = go * tanhf_fast(cn);
      *(_Float16*)((char*)hbW + wr_off[r]) = (_Float16)hn;
      if (t == LL - 1)
        h_out[(size_t)(n0 + g4 * 4 + r) * HH + w * 16 + cc] = hn;
      ewA[r] = ewN[r];
    }
    __syncthreads();  // h(t) complete before any wave reads it at t+1
  }
}

// ---------------------------------------------------------------------------
// Graph plumbing (unchanged from passing round)
// ---------------------------------------------------------------------------
__global__ __launch_bounds__(256) void deg_kernel(
    const int* __restrict__ src, const int* __restrict__ dst,
    int* __restrict__ deg_out, int* __restrict__ deg_in) {
  int i = blockIdx.x * 256 + threadIdx.x;
  if (i < EE) {
    atomicAdd(&deg_out[src[i]], 1);
    atomicAdd(&deg_in[dst[i]], 1);
  }
}

__global__ __launch_bounds__(1024) void scan_kernel(
    const int* __restrict__ deg_in, int* __restrict__ row_off) {
  __shared__ int partial[1024];
  const int tid = threadIdx.x;
  constexpr int CH = 20;
  int base = tid * CH;
  int local[CH];
  int s = 0;
#pragma unroll
  for (int i = 0; i < CH; ++i) {
    int v = (base + i < NN) ? deg_in[base + i] : 0;
    local[i] = s;
    s += v;
  }
  partial[tid] = s;
  __syncthreads();
  for (int off = 1; off < 1024; off <<= 1) {
    int v = (tid >= off) ? partial[tid - off] : 0;
    __syncthreads();
    partial[tid] += v;
    __syncthreads();
  }
  int pre = (tid > 0) ? partial[tid - 1] : 0;
#pragma unroll
  for (int i = 0; i < CH; ++i)
    if (base + i < NN) row_off[base + i] = pre + local[i];
  if (tid == 1023) row_off[NN] = partial[1023];
}

__global__ __launch_bounds__(256) void norm_kernel(
    const int* __restrict__ deg_out, const int* __restrict__ deg_in,
    float* __restrict__ n_src, float* __restrict__ n_dst) {
  int i = blockIdx.x * 256 + threadIdx.x;
  if (i >= NN) return;
  int dro = deg_out[i], dri = deg_in[i];
  n_src[i] = (dro > 0) ? 1.0f / sqrtf((float)dro) : 1.0f;
  n_dst[i] = (dri > 0) ? 1.0f / sqrtf((float)dri) : 1.0f;
}

__global__ __launch_bounds__(256) void fill_kernel(
    const int* __restrict__ src, const int* __restrict__ dst,
    const int* __restrict__ row_off, int* __restrict__ cursor,
    int* __restrict__ csr_src) {
  int i = blockIdx.x * 256 + threadIdx.x;
  if (i < EE) {
    int d = dst[i];
    int pos = atomicAdd(&cursor[d], 1);
    csr_src[row_off[d] + pos] = src[i];
  }
}

__global__ __launch_bounds__(256) void agg1_kernel(
    const float* __restrict__ h, const int* __restrict__ csr,
    const int* __restrict__ roff, const float* __restrict__ nsrc,
    const float* __restrict__ ndst, float* __restrict__ agg) {
  int node = blockIdx.x * 4 + (threadIdx.x >> 6);
  int lane = threadIdx.x & 63;
  if (node >= NN) return;
  int beg = roff[node], end = roff[node + 1];
  float a = 0.0f;
  int e = beg;
  for (; e + 4 <= end; e += 4) {
    int s0 = csr[e], s1 = csr[e + 1], s2 = csr[e + 2], s3 = csr[e + 3];
    float w0 = nsrc[s0], w1 = nsrc[s1], w2 = nsrc[s2], w3 = nsrc[s3];
    a += h[(size_t)s0 * HH + lane] * w0;
    a += h[(size_t)s1 * HH + lane] * w1;
    a += h[(size_t)s2 * HH + lane] * w2;
    a += h[(size_t)s3 * HH + lane] * w3;
  }
  for (; e < end; ++e) {
    int s = csr[e];
    a += h[(size_t)s * HH + lane] * nsrc[s];
  }
  agg[(size_t)node * HH + lane] = a * ndst[node];
}

__global__ __launch_bounds__(256) void gemm16_kernel(
    const float* __restrict__ A, const float* __restrict__ W2,
    float* __restrict__ z) {
  __shared__ float w[NHID * NCLS];
  for (int i = threadIdx.x; i < NHID * NCLS; i += 256) w[i] = W2[i];
  __syncthreads();
  int node = blockIdx.x * 16 + (threadIdx.x >> 4);
  int j = threadIdx.x & 15;
  if (node >= NN) return;
  const float* a = A + (size_t)node * NHID;
  float acc = 0.0f;
#pragma unroll 8
  for (int k = 0; k < NHID; k += 4) {
    float4 av = *(const float4*)(a + k);
    acc += av.x * w[(k + 0) * NCLS + j] + av.y * w[(k + 1) * NCLS + j] +
           av.z * w[(k + 2) * NCLS + j] + av.w * w[(k + 3) * NCLS + j];
  }
  z[(size_t)node * NCLS + j] = acc;
}

__global__ __launch_bounds__(256) void agg2_kernel(
    const float* __restrict__ z, const int* __restrict__ csr,
    const int* __restrict__ roff, const float* __restrict__ nsrc,
    const float* __restrict__ ndst, const float* __restrict__ b2,
    float* __restrict__ out) {
  int node = blockIdx.x * 4 + (threadIdx.x >> 6);
  int lane = threadIdx.x & 63;
  if (node >= NN) return;
  int dim = lane & 15, es = lane >> 4;
  int beg = roff[node], end = roff[node + 1];
  float a = 0.0f;
  for (int e = beg + es; e < end; e += 4) {
    int s = csr[e];
    a += z[(size_t)s * NCLS + dim] * nsrc[s];
  }
  a += __shfl_xor(a, 16, 64);
  a += __shfl_xor(a, 32, 64);
  if (lane < 16) out[(size_t)node * NCLS + dim] = ndst[node] * a + b2[dim];
}

// ---------------------------------------------------------------------------
extern "C" void kernel_launch(void* const* d_in, const int* in_sizes, int n_in,
                              void* d_out, int out_size, void* d_ws,
                              size_t ws_size, hipStream_t stream) {
  const int*   features = (const int*)d_in[0];
  const int*   src      = (const int*)d_in[1];
  const int*   dst      = (const int*)d_in[2];
  const float* emb      = (const float*)d_in[3];
  const float* W_ih     = (const float*)d_in[4];
  const float* W_hh     = (const float*)d_in[5];
  const float* b_ih     = (const float*)d_in[6];
  const float* b_hh     = (const float*)d_in[7];
  const float* W1       = (const float*)d_in[8];
  const float* b1       = (const float*)d_in[9];
  const float* W2       = (const float*)d_in[10];
  const float* b2       = (const float*)d_in[11];
  float* outp = (float*)d_out;

  // workspace layout (bytes). embW2 region is reused post-LSTM for agg/out1/z.
  char* ws = (char*)d_ws;
  float* embW2   = (float*)(ws + 0);          // 32,768,000
  float* agg     = (float*)(ws + 0);          // alias, post-LSTM
  float* out1    = (float*)(ws + 5120000);    // alias
  float* z       = (float*)(ws + 25600000);   // alias
  float* h       = (float*)(ws + 32768000);   // 5,120,000
  int*   deg_out = (int*)(ws + 37888000);
  int*   deg_in  = (int*)(ws + 37968000);
  int*   cursor  = (int*)(ws + 38048000);
  int*   row_off = (int*)(ws + 38128000);
  float* n_src   = (float*)(ws + 38208016);
  float* n_dst   = (float*)(ws + 38288016);
  int*   csr     = (int*)(ws + 38368016);     // -> end 40,928,016

  hipMemsetAsync(ws + 37888000, 0, 240000, stream);

  // embW2 = perm(emb @ W_ih^T + b_ih + b_hh)   [32000 x 256]
  gemm_kernel<true, false, true, true><<<dim3(4, 500), 256, 0, stream>>>(
      emb, W_ih, b_ih, b_hh, embW2, VV, FH, IND);

  // MFMA LSTM (4-wave d-split) -> final hidden h [20000 x 64]
  lstm_mfma4_kernel<<<1250, 256, 0, stream>>>(features, embW2, W_hh, h);

  // graph degrees / CSR
  deg_kernel<<<2500, 256, 0, stream>>>(src, dst, deg_out, deg_in);
  scan_kernel<<<1, 1024, 0, stream>>>(deg_in, row_off);
  norm_kernel<<<79, 256, 0, stream>>>(deg_out, deg_in, n_src, n_dst);
  fill_kernel<<<2500, 256, 0, stream>>>(src, dst, row_off, cursor, csr);

  // conv1: aggregate then linear+relu
  agg1_kernel<<<5000, 256, 0, stream>>>(h, csr, row_off, n_src, n_dst, agg);
  gemm_kernel<false, true, false, false><<<dim3(4, 313), 256, 0, stream>>>(
      agg, W1, b1, nullptr, out1, NN, NHID, HH);

  // conv2: push W2 through the (linear) aggregation
  gemm16_kernel<<<1250, 256, 0, stream>>>(out1, W2, z);
  agg2_kernel<<<5000, 256, 0, stream>>>(z, csr, row_off, n_src, n_dst, b2, outp);
}

// Round 7
// 470.874 us; speedup vs baseline: 2.3192x; 1.1035x over previous
//
#include <hip/hip_runtime.h>
#include <cstdint>
#include <cstddef>

// Problem constants (match reference)
#define NN   20000   // nodes
#define LL   50      // seq len
#define IND  128     // input dim
#define HH   64      // hidden
#define FH   256     // 4*H
#define NHID 256     // hidden layer of conv1
#define NCLS 16      // classes
#define VV   32000   // vocab
#define EE   640000  // edges

typedef _Float16 f16x8 __attribute__((ext_vector_type(8)));
typedef float    f32x4 __attribute__((ext_vector_type(4)));

// hardware v_rcp_f32 (~1 ulp): avoids the ~10-instr exact-division sequence
__device__ __forceinline__ float fast_rcp(float x) {
#if __has_builtin(__builtin_amdgcn_rcpf)
  return __builtin_amdgcn_rcpf(x);
#else
  return 1.0f / x;
#endif
}
__device__ __forceinline__ float sigmf(float x) {
  return fast_rcp(1.0f + __expf(-x));   // v_mul+v_exp+v_add+v_rcp
}
// overflow-safe tanh, rcp-based
__device__ __forceinline__ float tanhf_fast(float x) {
  float ax = fabsf(x);
  float t = __expf(-2.0f * ax);
  float r = (1.0f - t) * fast_rcp(1.0f + t);
  return copysignf(r, x);
}

// ---------------------------------------------------------------------------
// Generic tiled fp32 GEMM: C[M][Nc] = A[M][K] @ B (+bias1 [+bias2] [relu])
// B_IS_NK: B stored row-major [Nc][K] (C = A @ B^T); else B is [K][Nc].
// PERM: store column j at nn = ((j>>4)&3)*64 + (j&15)*4 + (j>>6)
//       (embW2 layout: [dt][cc][gate] -> per-(node,d) gate quad is one float4
//        AND 16 consecutive cc lanes read one contiguous 256B slice).
// ---------------------------------------------------------------------------
template <bool B_IS_NK, bool RELU, bool TWO_BIAS, bool PERM>
__global__ __launch_bounds__(256) void gemm_kernel(
    const float* __restrict__ A, const float* __restrict__ B,
    const float* __restrict__ bias1, const float* __restrict__ bias2,
    float* __restrict__ C, int M, int Ncols, int K) {
  __shared__ float As[64 * 17];
  __shared__ float Bs[16 * 68];
  const int tid = threadIdx.x;
  const int tx = tid & 15, ty = tid >> 4;
  const int m0 = blockIdx.y * 64, n0 = blockIdx.x * 64;

  float acc[4][4];
#pragma unroll
  for (int i = 0; i < 4; ++i)
#pragma unroll
    for (int j = 0; j < 4; ++j) acc[i][j] = 0.0f;

  for (int k0 = 0; k0 < K; k0 += 16) {
    {
      int row = tid >> 2, c4 = tid & 3;
      float4 v = make_float4(0.f, 0.f, 0.f, 0.f);
      if (m0 + row < M)
        v = *(const float4*)(A + (size_t)(m0 + row) * K + k0 + c4 * 4);
      As[row * 17 + c4 * 4 + 0] = v.x;
      As[row * 17 + c4 * 4 + 1] = v.y;
      As[row * 17 + c4 * 4 + 2] = v.z;
      As[row * 17 + c4 * 4 + 3] = v.w;
    }
    if constexpr (B_IS_NK) {
      int n = tid >> 2, c4 = tid & 3;
      float4 v = *(const float4*)(B + (size_t)(n0 + n) * K + k0 + c4 * 4);
      Bs[(c4 * 4 + 0) * 68 + n] = v.x;
      Bs[(c4 * 4 + 1) * 68 + n] = v.y;
      Bs[(c4 * 4 + 2) * 68 + n] = v.z;
      Bs[(c4 * 4 + 3) * 68 + n] = v.w;
    } else {
      int k = tid >> 4, n4 = tid & 15;
      float4 v = *(const float4*)(B + (size_t)(k0 + k) * Ncols + n0 + n4 * 4);
      *(float4*)(Bs + k * 68 + n4 * 4) = v;
    }
    __syncthreads();
#pragma unroll
    for (int k = 0; k < 16; ++k) {
      float4 bv = *(const float4*)(Bs + k * 68 + tx * 4);
      float a0 = As[(ty * 4 + 0) * 17 + k];
      float a1 = As[(ty * 4 + 1) * 17 + k];
      float a2 = As[(ty * 4 + 2) * 17 + k];
      float a3 = As[(ty * 4 + 3) * 17 + k];
      acc[0][0] += a0 * bv.x; acc[0][1] += a0 * bv.y; acc[0][2] += a0 * bv.z; acc[0][3] += a0 * bv.w;
      acc[1][0] += a1 * bv.x; acc[1][1] += a1 * bv.y; acc[1][2] += a1 * bv.z; acc[1][3] += a1 * bv.w;
      acc[2][0] += a2 * bv.x; acc[2][1] += a2 * bv.y; acc[2][2] += a2 * bv.z; acc[2][3] += a2 * bv.w;
      acc[3][0] += a3 * bv.x; acc[3][1] += a3 * bv.y; acc[3][2] += a3 * bv.z; acc[3][3] += a3 * bv.w;
    }
    __syncthreads();
  }
#pragma unroll
  for (int i = 0; i < 4; ++i) {
    int m = m0 + ty * 4 + i;
    if (m >= M) continue;
#pragma unroll
    for (int j = 0; j < 4; ++j) {
      int n = n0 + tx * 4 + j;
      float v = acc[i][j] + bias1[n];
      if constexpr (TWO_BIAS) v += bias2[n];
      if constexpr (RELU) v = fmaxf(v, 0.0f);
      int nn = PERM ? (((n >> 4) & 3) * 64 + (n & 15) * 4 + (n >> 6)) : n;
      C[(size_t)m * Ncols + nn] = v;
    }
  }
}

// ---------------------------------------------------------------------------
// MFMA LSTM, 4-wave d-split: 1250 blocks x 256 threads (4 waves), 16 nodes
// per block, wave w owns d in [16w, 16w+16) for all 16 nodes.
// Per wave per step: 8 mfma_f32_16x16x32_f16 (4 gates x 2 k-halves), 4
// activation quads/thread (rcp-based, no fp32 div), 4 embW2 float4 gathers
// prefetched one full step ahead. h double-buffered in XOR-swizzled LDS;
// one barrier per step.
// D-layout: row=(lane>>4)*4+reg -> node, col=lane&15 -> d-within-tile.
// ---------------------------------------------------------------------------
__global__ __launch_bounds__(256) void lstm_mfma4_kernel(
    const int* __restrict__ feat, const float* __restrict__ embW2,
    const float* __restrict__ W_hh, float* __restrict__ h_out) {
  __shared__ __align__(16) _Float16 hbuf[2][16 * 64];
  __shared__ int fbuf[16 * LL];

  const int tid = threadIdx.x;
  const int l   = tid & 63;
  const int w   = tid >> 6;   // wave id = d-tile (0..3)
  const int cc  = l & 15;
  const int g4  = l >> 4;
  const int n0  = blockIdx.x * 16;

  // ---- B-frags for this wave's 4 gate col-tiles (cols g*64 + w*16 + cc)
  f16x8 Bf[4][2];
#pragma unroll
  for (int g = 0; g < 4; ++g)
#pragma unroll
    for (int kh = 0; kh < 2; ++kh) {
      const float* wp = W_hh + (g * 64 + w * 16 + cc) * 64 + kh * 32 + g4 * 8;
      float4 w0 = *(const float4*)(wp);
      float4 w1 = *(const float4*)(wp + 4);
      f16x8 b;
      b[0] = (_Float16)w0.x; b[1] = (_Float16)w0.y;
      b[2] = (_Float16)w0.z; b[3] = (_Float16)w0.w;
      b[4] = (_Float16)w1.x; b[5] = (_Float16)w1.y;
      b[6] = (_Float16)w1.z; b[7] = (_Float16)w1.w;
      Bf[g][kh] = b;
    }

  // ---- zero both h buffers (h(-1)=0), stage feature rows
  for (int i = tid; i < 2 * 16 * 64; i += 256) ((_Float16*)hbuf)[i] = (_Float16)0.0f;
  for (int i = tid; i < 16 * LL; i += 256) fbuf[i] = feat[n0 * LL + i];

  // ---- A-frag read offsets (swizzled, same layout as verified kernel)
  const int aoff = cc * 128;
  const int sb0  = ((g4    ) ^ (cc & 7)) << 4;
  const int sb1  = ((g4 + 4) ^ (cc & 7)) << 4;

  // ---- h write byte-offsets: n = g4*4+r, d = w*16+cc
  int wr_off[4];
#pragma unroll
  for (int r = 0; r < 4; ++r) {
    int n = g4 * 4 + r;
    int dgrp = w * 2 + (cc >> 3);
    wr_off[r] = n * 128 + ((dgrp ^ (n & 7)) << 4) + (cc & 7) * 2;
  }

  float c_reg[4];
#pragma unroll
  for (int r = 0; r < 4; ++r) c_reg[r] = 0.0f;

  __syncthreads();

  // ---- prologue: ew for t=0
  float4 ewA[4];
#pragma unroll
  for (int r = 0; r < 4; ++r) {
    int row = fbuf[(g4 * 4 + r) * LL + 0];
    ewA[r] = *(const float4*)(embW2 + (size_t)row * FH + w * 64 + cc * 4);
  }

  for (int t = 0; t < LL; ++t) {
    const char* hbR = (const char*)hbuf[t & 1];        // h(t-1)
    _Float16*   hbW = hbuf[(t & 1) ^ 1];               // h(t)

    f16x8 A0 = *(const f16x8*)(hbR + aoff + sb0);
    f16x8 A1 = *(const f16x8*)(hbR + aoff + sb1);

    // issue next step's ew (full-step latency hiding)
    const int tn = (t < LL - 1) ? t + 1 : t;
    float4 ewN[4];
#pragma unroll
    for (int r = 0; r < 4; ++r) {
      int row = fbuf[(g4 * 4 + r) * LL + tn];
      ewN[r] = *(const float4*)(embW2 + (size_t)row * FH + w * 64 + cc * 4);
    }

    f32x4 z = {0.f, 0.f, 0.f, 0.f};
    f32x4 aci = __builtin_amdgcn_mfma_f32_16x16x32_f16(A0, Bf[0][0], z, 0, 0, 0);
    aci = __builtin_amdgcn_mfma_f32_16x16x32_f16(A1, Bf[0][1], aci, 0, 0, 0);
    f32x4 acf = __builtin_amdgcn_mfma_f32_16x16x32_f16(A0, Bf[1][0], z, 0, 0, 0);
    acf = __builtin_amdgcn_mfma_f32_16x16x32_f16(A1, Bf[1][1], acf, 0, 0, 0);
    f32x4 acg = __builtin_amdgcn_mfma_f32_16x16x32_f16(A0, Bf[2][0], z, 0, 0, 0);
    acg = __builtin_amdgcn_mfma_f32_16x16x32_f16(A1, Bf[2][1], acg, 0, 0, 0);
    f32x4 aco = __builtin_amdgcn_mfma_f32_16x16x32_f16(A0, Bf[3][0], z, 0, 0, 0);
    aco = __builtin_amdgcn_mfma_f32_16x16x32_f16(A1, Bf[3][1], aco, 0, 0, 0);

    // activation: acc component r -> node g4*4+r, at d = w*16+cc
#pragma unroll
    for (int r = 0; r < 4; ++r) {
      float gi = sigmf(aci[r] + ewA[r].x);
      float gf = sigmf(acf[r] + ewA[r].y);
      float gg = tanhf_fast(acg[r] + ewA[r].z);
      float go = sigmf(aco[r] + ewA[r].w);
      float cn = gf * c_reg[r] + gi * gg;
      c_reg[r] = cn;
      float hn = go * tanhf_fast(cn);
      *(_Float16*)((char*)hbW + wr_off[r]) = (_Float16)hn;
      if (t == LL - 1)
        h_out[(size_t)(n0 + g4 * 4 + r) * HH + w * 16 + cc] = hn;
      ewA[r] = ewN[r];
    }
    __syncthreads();  // h(t) complete before any wave reads it at t+1
  }
}

// ---------------------------------------------------------------------------
// Graph plumbing
// ---------------------------------------------------------------------------
__global__ __launch_bounds__(256) void deg_kernel(
    const int* __restrict__ src, const int* __restrict__ dst,
    int* __restrict__ deg_out, int* __restrict__ deg_in) {
  int i = blockIdx.x * 256 + threadIdx.x;
  if (i < EE) {
    atomicAdd(&deg_out[src[i]], 1);
    atomicAdd(&deg_in[dst[i]], 1);
  }
}

__global__ __launch_bounds__(1024) void scan_kernel(
    const int* __restrict__ deg_in, int* __restrict__ row_off) {
  __shared__ int partial[1024];
  const int tid = threadIdx.x;
  constexpr int CH = 20;
  int base = tid * CH;
  int local[CH];
  int s = 0;
#pragma unroll
  for (int i = 0; i < CH; ++i) {
    int v = (base + i < NN) ? deg_in[base + i] : 0;
    local[i] = s;
    s += v;
  }
  partial[tid] = s;
  __syncthreads();
  for (int off = 1; off < 1024; off <<= 1) {
    int v = (tid >= off) ? partial[tid - off] : 0;
    __syncthreads();
    partial[tid] += v;
    __syncthreads();
  }
  int pre = (tid > 0) ? partial[tid - 1] : 0;
#pragma unroll
  for (int i = 0; i < CH; ++i)
    if (base + i < NN) row_off[base + i] = pre + local[i];
  if (tid == 1023) row_off[NN] = partial[1023];
}

__global__ __launch_bounds__(256) void norm_kernel(
    const int* __restrict__ deg_out, const int* __restrict__ deg_in,
    float* __restrict__ n_src, float* __restrict__ n_dst) {
  int i = blockIdx.x * 256 + threadIdx.x;
  if (i >= NN) return;
  int dro = deg_out[i], dri = deg_in[i];
  n_src[i] = (dro > 0) ? rsqrtf((float)dro) : 1.0f;
  n_dst[i] = (dri > 0) ? rsqrtf((float)dri) : 1.0f;
}

__global__ __launch_bounds__(256) void fill_kernel(
    const int* __restrict__ src, const int* __restrict__ dst,
    const int* __restrict__ row_off, int* __restrict__ cursor,
    int* __restrict__ csr_src) {
  int i = blockIdx.x * 256 + threadIdx.x;
  if (i < EE) {
    int d = dst[i];
    int pos = atomicAdd(&cursor[d], 1);
    csr_src[row_off[d] + pos] = src[i];
  }
}

__global__ __launch_bounds__(256) void agg1_kernel(
    const float* __restrict__ h, const int* __restrict__ csr,
    const int* __restrict__ roff, const float* __restrict__ nsrc,
    const float* __restrict__ ndst, float* __restrict__ agg) {
  int node = blockIdx.x * 4 + (threadIdx.x >> 6);
  int lane = threadIdx.x & 63;
  if (node >= NN) return;
  int beg = roff[node], end = roff[node + 1];
  float a = 0.0f;
  int e = beg;
  for (; e + 4 <= end; e += 4) {
    int s0 = csr[e], s1 = csr[e + 1], s2 = csr[e + 2], s3 = csr[e + 3];
    float w0 = nsrc[s0], w1 = nsrc[s1], w2 = nsrc[s2], w3 = nsrc[s3];
    a += h[(size_t)s0 * HH + lane] * w0;
    a += h[(size_t)s1 * HH + lane] * w1;
    a += h[(size_t)s2 * HH + lane] * w2;
    a += h[(size_t)s3 * HH + lane] * w3;
  }
  for (; e < end; ++e) {
    int s = csr[e];
    a += h[(size_t)s * HH + lane] * nsrc[s];
  }
  agg[(size_t)node * HH + lane] = a * ndst[node];
}

__global__ __launch_bounds__(256) void gemm16_kernel(
    const float* __restrict__ A, const float* __restrict__ W2,
    float* __restrict__ z) {
  __shared__ float w[NHID * NCLS];
  for (int i = threadIdx.x; i < NHID * NCLS; i += 256) w[i] = W2[i];
  __syncthreads();
  int node = blockIdx.x * 16 + (threadIdx.x >> 4);
  int j = threadIdx.x & 15;
  if (node >= NN) return;
  const float* a = A + (size_t)node * NHID;
  float acc = 0.0f;
#pragma unroll 8
  for (int k = 0; k < NHID; k += 4) {
    float4 av = *(const float4*)(a + k);
    acc += av.x * w[(k + 0) * NCLS + j] + av.y * w[(k + 1) * NCLS + j] +
           av.z * w[(k + 2) * NCLS + j] + av.w * w[(k + 3) * NCLS + j];
  }
  z[(size_t)node * NCLS + j] = acc;
}

__global__ __launch_bounds__(256) void agg2_kernel(
    const float* __restrict__ z, const int* __restrict__ csr,
    const int* __restrict__ roff, const float* __restrict__ nsrc,
    const float* __restrict__ ndst, const float* __restrict__ b2,
    float* __restrict__ out) {
  int node = blockIdx.x * 4 + (threadIdx.x >> 6);
  int lane = threadIdx.x & 63;
  if (node >= NN) return;
  int dim = lane & 15, es = lane >> 4;
  int beg = roff[node], end = roff[node + 1];
  float a = 0.0f;
  for (int e = beg + es; e < end; e += 4) {
    int s = csr[e];
    a += z[(size_t)s * NCLS + dim] * nsrc[s];
  }
  a += __shfl_xor(a, 16, 64);
  a += __shfl_xor(a, 32, 64);
  if (lane < 16) out[(size_t)node * NCLS + dim] = ndst[node] * a + b2[dim];
}

// ---------------------------------------------------------------------------
extern "C" void kernel_launch(void* const* d_in, const int* in_sizes, int n_in,
                              void* d_out, int out_size, void* d_ws,
                              size_t ws_size, hipStream_t stream) {
  const int*   features = (const int*)d_in[0];
  const int*   src      = (const int*)d_in[1];
  const int*   dst      = (const int*)d_in[2];
  const float* emb      = (const float*)d_in[3];
  const float* W_ih     = (const float*)d_in[4];
  const float* W_hh     = (const float*)d_in[5];
  const float* b_ih     = (const float*)d_in[6];
  const float* b_hh     = (const float*)d_in[7];
  const float* W1       = (const float*)d_in[8];
  const float* b1       = (const float*)d_in[9];
  const float* W2       = (const float*)d_in[10];
  const float* b2       = (const float*)d_in[11];
  float* outp = (float*)d_out;

  // workspace layout (bytes). embW2 region is reused post-LSTM for agg/out1/z.
  char* ws = (char*)d_ws;
  float* embW2   = (float*)(ws + 0);          // 32,768,000
  float* agg     = (float*)(ws + 0);          // alias, post-LSTM
  float* out1    = (float*)(ws + 5120000);    // alias
  float* z       = (float*)(ws + 25600000);   // alias
  float* h       = (float*)(ws + 32768000);   // 5,120,000
  int*   deg_out = (int*)(ws + 37888000);
  int*   deg_in  = (int*)(ws + 37968000);
  int*   cursor  = (int*)(ws + 38048000);
  int*   row_off = (int*)(ws + 38128000);
  float* n_src   = (float*)(ws + 38208016);
  float* n_dst   = (float*)(ws + 38288016);
  int*   csr     = (int*)(ws + 38368016);     // -> end 40,928,016

  hipMemsetAsync(ws + 37888000, 0, 240000, stream);

  // embW2 = perm(emb @ W_ih^T + b_ih + b_hh)   [32000 x 256]
  gemm_kernel<true, false, true, true><<<dim3(4, 500), 256, 0, stream>>>(
      emb, W_ih, b_ih, b_hh, embW2, VV, FH, IND);

  // MFMA LSTM (4-wave d-split) -> final hidden h [20000 x 64]
  lstm_mfma4_kernel<<<1250, 256, 0, stream>>>(features, embW2, W_hh, h);

  // graph degrees / CSR
  deg_kernel<<<2500, 256, 0, stream>>>(src, dst, deg_out, deg_in);
  scan_kernel<<<1, 1024, 0, stream>>>(deg_in, row_off);
  norm_kernel<<<79, 256, 0, stream>>>(deg_out, deg_in, n_src, n_dst);
  fill_kernel<<<2500, 256, 0, stream>>>(src, dst, row_off, cursor, csr);

  // conv1: aggregate then linear+relu
  agg1_kernel<<<5000, 256, 0, stream>>>(h, csr, row_off, n_src, n_dst, agg);
  gemm_kernel<false, true, false, false><<<dim3(4, 313), 256, 0, stream>>>(
      agg, W1, b1, nullptr, out1, NN, NHID, HH);

  // conv2: push W2 through the (linear) aggregation
  gemm16_kernel<<<1250, 256, 0, stream>>>(out1, W2, z);
  agg2_kernel<<<5000, 256, 0, stream>>>(z, csr, row_off, n_src, n_dst, b2, outp);
}

// Round 9
// 447.398 us; speedup vs baseline: 2.4409x; 1.0525x over previous
//
#include <hip/hip_runtime.h>
#include <cstdint>
#include <cstddef>

// Problem constants (match reference)
#define NN   20000   // nodes
#define LL   50      // seq len
#define IND  128     // input dim
#define HH   64      // hidden
#define FH   256     // 4*H
#define NHID 256     // hidden layer of conv1
#define NCLS 16      // classes
#define VV   32000   // vocab
#define EE   640000  // edges

typedef _Float16 f16x8 __attribute__((ext_vector_type(8)));
typedef float    f32x4 __attribute__((ext_vector_type(4)));

// hardware v_rcp_f32 (~1 ulp): avoids the ~10-instr exact-division sequence
__device__ __forceinline__ float fast_rcp(float x) {
#if __has_builtin(__builtin_amdgcn_rcpf)
  return __builtin_amdgcn_rcpf(x);
#else
  return 1.0f / x;
#endif
}
__device__ __forceinline__ float sigmf(float x) {
  return fast_rcp(1.0f + __expf(-x));   // v_mul+v_exp+v_add+v_rcp
}
// overflow-safe tanh, rcp-based
__device__ __forceinline__ float tanhf_fast(float x) {
  float ax = fabsf(x);
  float t = __expf(-2.0f * ax);
  float r = (1.0f - t) * fast_rcp(1.0f + t);
  return copysignf(r, x);
}

// ---------------------------------------------------------------------------
// Generic tiled fp32 GEMM: C[M][Nc] = A[M][K] @ B (+bias1 [+bias2] [relu])
// B_IS_NK: B stored row-major [Nc][K] (C = A @ B^T); else B is [K][Nc].
// PERM (load-side): output column nn holds mathematical column
//   j(nn) = (nn&3)*64 + ((nn>>6)&3)*16 + ((nn>>2)&15)
// i.e. embW2 layout [dt][cc][gate] with LINEAR coalesced stores; the
// permutation is applied by staging W_ih row j(nn) and bias[j(nn)].
// (Inverse of nn(j)=dt*64+cc*4+g for j=g*64+dt*16+cc — round-trip verified.)
// ---------------------------------------------------------------------------
__device__ __forceinline__ int perm_inv(int nn) {
  return (nn & 3) * 64 + ((nn >> 6) & 3) * 16 + ((nn >> 2) & 15);
}

template <bool B_IS_NK, bool RELU, bool TWO_BIAS, bool PERM>
__global__ __launch_bounds__(256) void gemm_kernel(
    const float* __restrict__ A, const float* __restrict__ B,
    const float* __restrict__ bias1, const float* __restrict__ bias2,
    float* __restrict__ C, int M, int Ncols, int K) {
  __shared__ float As[64 * 17];
  __shared__ float Bs[16 * 68];
  const int tid = threadIdx.x;
  const int tx = tid & 15, ty = tid >> 4;
  const int m0 = blockIdx.y * 64, n0 = blockIdx.x * 64;

  float acc[4][4];
#pragma unroll
  for (int i = 0; i < 4; ++i)
#pragma unroll
    for (int j = 0; j < 4; ++j) acc[i][j] = 0.0f;

  for (int k0 = 0; k0 < K; k0 += 16) {
    {
      int row = tid >> 2, c4 = tid & 3;
      float4 v = make_float4(0.f, 0.f, 0.f, 0.f);
      if (m0 + row < M)
        v = *(const float4*)(A + (size_t)(m0 + row) * K + k0 + c4 * 4);
      As[row * 17 + c4 * 4 + 0] = v.x;
      As[row * 17 + c4 * 4 + 1] = v.y;
      As[row * 17 + c4 * 4 + 2] = v.z;
      As[row * 17 + c4 * 4 + 3] = v.w;
    }
    if constexpr (B_IS_NK) {
      int n = tid >> 2, c4 = tid & 3;
      int gn = n0 + n;
      if constexpr (PERM) gn = perm_inv(gn);
      float4 v = *(const float4*)(B + (size_t)gn * K + k0 + c4 * 4);
      Bs[(c4 * 4 + 0) * 68 + n] = v.x;
      Bs[(c4 * 4 + 1) * 68 + n] = v.y;
      Bs[(c4 * 4 + 2) * 68 + n] = v.z;
      Bs[(c4 * 4 + 3) * 68 + n] = v.w;
    } else {
      int k = tid >> 4, n4 = tid & 15;
      float4 v = *(const float4*)(B + (size_t)(k0 + k) * Ncols + n0 + n4 * 4);
      *(float4*)(Bs + k * 68 + n4 * 4) = v;
    }
    __syncthreads();
#pragma unroll
    for (int k = 0; k < 16; ++k) {
      float4 bv = *(const float4*)(Bs + k * 68 + tx * 4);
      float a0 = As[(ty * 4 + 0) * 17 + k];
      float a1 = As[(ty * 4 + 1) * 17 + k];
      float a2 = As[(ty * 4 + 2) * 17 + k];
      float a3 = As[(ty * 4 + 3) * 17 + k];
      acc[0][0] += a0 * bv.x; acc[0][1] += a0 * bv.y; acc[0][2] += a0 * bv.z; acc[0][3] += a0 * bv.w;
      acc[1][0] += a1 * bv.x; acc[1][1] += a1 * bv.y; acc[1][2] += a1 * bv.z; acc[1][3] += a1 * bv.w;
      acc[2][0] += a2 * bv.x; acc[2][1] += a2 * bv.y; acc[2][2] += a2 * bv.z; acc[2][3] += a2 * bv.w;
      acc[3][0] += a3 * bv.x; acc[3][1] += a3 * bv.y; acc[3][2] += a3 * bv.z; acc[3][3] += a3 * bv.w;
    }
    __syncthreads();
  }
#pragma unroll
  for (int i = 0; i < 4; ++i) {
    int m = m0 + ty * 4 + i;
    if (m >= M) continue;
#pragma unroll
    for (int j = 0; j < 4; ++j) {
      int n = n0 + tx * 4 + j;
      int bn = PERM ? perm_inv(n) : n;
      float v = acc[i][j] + bias1[bn];
      if constexpr (TWO_BIAS) v += bias2[bn];
      if constexpr (RELU) v = fmaxf(v, 0.0f);
      C[(size_t)m * Ncols + n] = v;   // linear, coalesced
    }
  }
}

// ---------------------------------------------------------------------------
// MFMA LSTM, 4-wave d-split: 1250 blocks x 256 threads (4 waves), 16 nodes
// per block, wave w owns d in [16w, 16w+16) for all 16 nodes.
// Per wave per step: 8 mfma_f32_16x16x32_f16 (4 gates x 2 k-halves), 4
// activation quads/thread (rcp-based, no fp32 div), 4 embW2 float4 gathers
// prefetched one full step ahead. h double-buffered in XOR-swizzled LDS;
// one barrier per step.
// D-layout: row=(lane>>4)*4+reg -> node, col=lane&15 -> d-within-tile.
// ---------------------------------------------------------------------------
__global__ __launch_bounds__(256) void lstm_mfma4_kernel(
    const int* __restrict__ feat, const float* __restrict__ embW2,
    const float* __restrict__ W_hh, float* __restrict__ h_out) {
  __shared__ __align__(16) _Float16 hbuf[2][16 * 64];
  __shared__ int fbuf[16 * LL];

  const int tid = threadIdx.x;
  const int l   = tid & 63;
  const int w   = tid >> 6;   // wave id = d-tile (0..3)
  const int cc  = l & 15;
  const int g4  = l >> 4;
  const int n0  = blockIdx.x * 16;

  // ---- B-frags for this wave's 4 gate col-tiles (cols g*64 + w*16 + cc)
  f16x8 Bf[4][2];
#pragma unroll
  for (int g = 0; g < 4; ++g)
#pragma unroll
    for (int kh = 0; kh < 2; ++kh) {
      const float* wp = W_hh + (g * 64 + w * 16 + cc) * 64 + kh * 32 + g4 * 8;
      float4 w0 = *(const float4*)(wp);
      float4 w1 = *(const float4*)(wp + 4);
      f16x8 b;
      b[0] = (_Float16)w0.x; b[1] = (_Float16)w0.y;
      b[2] = (_Float16)w0.z; b[3] = (_Float16)w0.w;
      b[4] = (_Float16)w1.x; b[5] = (_Float16)w1.y;
      b[6] = (_Float16)w1.z; b[7] = (_Float16)w1.w;
      Bf[g][kh] = b;
    }

  // ---- zero both h buffers (h(-1)=0), stage feature rows
  for (int i = tid; i < 2 * 16 * 64; i += 256) ((_Float16*)hbuf)[i] = (_Float16)0.0f;
  for (int i = tid; i < 16 * LL; i += 256) fbuf[i] = feat[n0 * LL + i];

  // ---- A-frag read offsets (swizzled, same layout as verified kernel)
  const int aoff = cc * 128;
  const int sb0  = ((g4    ) ^ (cc & 7)) << 4;
  const int sb1  = ((g4 + 4) ^ (cc & 7)) << 4;

  // ---- h write byte-offsets: n = g4*4+r, d = w*16+cc
  int wr_off[4];
#pragma unroll
  for (int r = 0; r < 4; ++r) {
    int n = g4 * 4 + r;
    int dgrp = w * 2 + (cc >> 3);
    wr_off[r] = n * 128 + ((dgrp ^ (n & 7)) << 4) + (cc & 7) * 2;
  }

  float c_reg[4];
#pragma unroll
  for (int r = 0; r < 4; ++r) c_reg[r] = 0.0f;

  __syncthreads();

  // ---- prologue: ew for t=0
  float4 ewA[4];
#pragma unroll
  for (int r = 0; r < 4; ++r) {
    int row = fbuf[(g4 * 4 + r) * LL + 0];
    ewA[r] = *(const float4*)(embW2 + (size_t)row * FH + w * 64 + cc * 4);
  }

  for (int t = 0; t < LL; ++t) {
    const char* hbR = (const char*)hbuf[t & 1];        // h(t-1)
    _Float16*   hbW = hbuf[(t & 1) ^ 1];               // h(t)

    f16x8 A0 = *(const f16x8*)(hbR + aoff + sb0);
    f16x8 A1 = *(const f16x8*)(hbR + aoff + sb1);

    // issue next step's ew (full-step latency hiding)
    const int tn = (t < LL - 1) ? t + 1 : t;
    float4 ewN[4];
#pragma unroll
    for (int r = 0; r < 4; ++r) {
      int row = fbuf[(g4 * 4 + r) * LL + tn];
      ewN[r] = *(const float4*)(embW2 + (size_t)row * FH + w * 64 + cc * 4);
    }

    f32x4 z = {0.f, 0.f, 0.f, 0.f};
    f32x4 aci = __builtin_amdgcn_mfma_f32_16x16x32_f16(A0, Bf[0][0], z, 0, 0, 0);
    aci = __builtin_amdgcn_mfma_f32_16x16x32_f16(A1, Bf[0][1], aci, 0, 0, 0);
    f32x4 acf = __builtin_amdgcn_mfma_f32_16x16x32_f16(A0, Bf[1][0], z, 0, 0, 0);
    acf = __builtin_amdgcn_mfma_f32_16x16x32_f16(A1, Bf[1][1], acf, 0, 0, 0);
    f32x4 acg = __builtin_amdgcn_mfma_f32_16x16x32_f16(A0, Bf[2][0], z, 0, 0, 0);
    acg = __builtin_amdgcn_mfma_f32_16x16x32_f16(A1, Bf[2][1], acg, 0, 0, 0);
    f32x4 aco = __builtin_amdgcn_mfma_f32_16x16x32_f16(A0, Bf[3][0], z, 0, 0, 0);
    aco = __builtin_amdgcn_mfma_f32_16x16x32_f16(A1, Bf[3][1], aco, 0, 0, 0);

    // activation: acc component r -> node g4*4+r, at d = w*16+cc
#pragma unroll
    for (int r = 0; r < 4; ++r) {
      float gi = sigmf(aci[r] + ewA[r].x);
      float gf = sigmf(acf[r] + ewA[r].y);
      float gg = tanhf_fast(acg[r] + ewA[r].z);
      float go = sigmf(aco[r] + ewA[r].w);
      float cn = gf * c_reg[r] + gi * gg;
      c_reg[r] = cn;
      float hn = go * tanhf_fast(cn);
      *(_Float16*)((char*)hbW + wr_off[r]) = (_Float16)hn;
      if (t == LL - 1)
        h_out[(size_t)(n0 + g4 * 4 + r) * HH + w * 16 + cc] = hn;
      ewA[r] = ewN[r];
    }
    __syncthreads();  // h(t) complete before any wave reads it at t+1
  }
}

// ---------------------------------------------------------------------------
// Graph plumbing
// ---------------------------------------------------------------------------
__global__ __launch_bounds__(256) void deg_kernel(
    const int* __restrict__ src, const int* __restrict__ dst,
    int* __restrict__ deg_out, int* __restrict__ deg_in) {
  int i = blockIdx.x * 256 + threadIdx.x;
  if (i < EE) {
    atomicAdd(&deg_out[src[i]], 1);
    atomicAdd(&deg_in[dst[i]], 1);
  }
}

__global__ __launch_bounds__(1024) void scan_kernel(
    const int* __restrict__ deg_in, int* __restrict__ row_off) {
  __shared__ int partial[1024];
  const int tid = threadIdx.x;
  constexpr int CH = 20;
  int base = tid * CH;
  int local[CH];
  int s = 0;
#pragma unroll
  for (int i = 0; i < CH; ++i) {
    int v = (base + i < NN) ? deg_in[base + i] : 0;
    local[i] = s;
    s += v;
  }
  partial[tid] = s;
  __syncthreads();
  for (int off = 1; off < 1024; off <<= 1) {
    int v = (tid >= off) ? partial[tid - off] : 0;
    __syncthreads();
    partial[tid] += v;
    __syncthreads();
  }
  int pre = (tid > 0) ? partial[tid - 1] : 0;
#pragma unroll
  for (int i = 0; i < CH; ++i)
    if (base + i < NN) row_off[base + i] = pre + local[i];
  if (tid == 1023) row_off[NN] = partial[1023];
}

__global__ __launch_bounds__(256) void norm_kernel(
    const int* __restrict__ deg_out, const int* __restrict__ deg_in,
    float* __restrict__ n_src, float* __restrict__ n_dst) {
  int i = blockIdx.x * 256 + threadIdx.x;
  if (i >= NN) return;
  int dro = deg_out[i], dri = deg_in[i];
  n_src[i] = (dro > 0) ? rsqrtf((float)dro) : 1.0f;
  n_dst[i] = (dri > 0) ? rsqrtf((float)dri) : 1.0f;
}

__global__ __launch_bounds__(256) void fill_kernel(
    const int* __restrict__ src, const int* __restrict__ dst,
    const int* __restrict__ row_off, int* __restrict__ cursor,
    int* __restrict__ csr_src) {
  int i = blockIdx.x * 256 + threadIdx.x;
  if (i < EE) {
    int d = dst[i];
    int pos = atomicAdd(&cursor[d], 1);
    csr_src[row_off[d] + pos] = src[i];
  }
}

__global__ __launch_bounds__(256) void agg1_kernel(
    const float* __restrict__ h, const int* __restrict__ csr,
    const int* __restrict__ roff, const float* __restrict__ nsrc,
    const float* __restrict__ ndst, float* __restrict__ agg) {
  int node = blockIdx.x * 4 + (threadIdx.x >> 6);
  int lane = threadIdx.x & 63;
  if (node >= NN) return;
  int beg = roff[node], end = roff[node + 1];
  float a = 0.0f;
  int e = beg;
  for (; e + 4 <= end; e += 4) {
    int s0 = csr[e], s1 = csr[e + 1], s2 = csr[e + 2], s3 = csr[e + 3];
    float w0 = nsrc[s0], w1 = nsrc[s1], w2 = nsrc[s2], w3 = nsrc[s3];
    a += h[(size_t)s0 * HH + lane] * w0;
    a += h[(size_t)s1 * HH + lane] * w1;
    a += h[(size_t)s2 * HH + lane] * w2;
    a += h[(size_t)s3 * HH + lane] * w3;
  }
  for (; e < end; ++e) {
    int s = csr[e];
    a += h[(size_t)s * HH + lane] * nsrc[s];
  }
  agg[(size_t)node * HH + lane] = a * ndst[node];
}

__global__ __launch_bounds__(256) void gemm16_kernel(
    const float* __restrict__ A, const float* __restrict__ W2,
    float* __restrict__ z) {
  __shared__ float w[NHID * NCLS];
  for (int i = threadIdx.x; i < NHID * NCLS; i += 256) w[i] = W2[i];
  __syncthreads();
  int node = blockIdx.x * 16 + (threadIdx.x >> 4);
  int j = threadIdx.x & 15;
  if (node >= NN) return;
  const float* a = A + (size_t)node * NHID;
  float acc = 0.0f;
#pragma unroll 8
  for (int k = 0; k < NHID; k += 4) {
    float4 av = *(const float4*)(a + k);
    acc += av.x * w[(k + 0) * NCLS + j] + av.y * w[(k + 1) * NCLS + j] +
           av.z * w[(k + 2) * NCLS + j] + av.w * w[(k + 3) * NCLS + j];
  }
  z[(size_t)node * NCLS + j] = acc;
}

__global__ __launch_bounds__(256) void agg2_kernel(
    const float* __restrict__ z, const int* __restrict__ csr,
    const int* __restrict__ roff, const float* __restrict__ nsrc,
    const float* __restrict__ ndst, const float* __restrict__ b2,
    float* __restrict__ out) {
  int node = blockIdx.x * 4 + (threadIdx.x >> 6);
  int lane = threadIdx.x & 63;
  if (node >= NN) return;
  int dim = lane & 15, es = lane >> 4;
  int beg = roff[node], end = roff[node + 1];
  float a = 0.0f;
  for (int e = beg + es; e < end; e += 4) {
    int s = csr[e];
    a += z[(size_t)s * NCLS + dim] * nsrc[s];
  }
  a += __shfl_xor(a, 16, 64);
  a += __shfl_xor(a, 32, 64);
  if (lane < 16) out[(size_t)node * NCLS + dim] = ndst[node] * a + b2[dim];
}

// ---------------------------------------------------------------------------
extern "C" void kernel_launch(void* const* d_in, const int* in_sizes, int n_in,
                              void* d_out, int out_size, void* d_ws,
                              size_t ws_size, hipStream_t stream) {
  const int*   features = (const int*)d_in[0];
  const int*   src      = (const int*)d_in[1];
  const int*   dst      = (const int*)d_in[2];
  const float* emb      = (const float*)d_in[3];
  const float* W_ih     = (const float*)d_in[4];
  const float* W_hh     = (const float*)d_in[5];
  const float* b_ih     = (const float*)d_in[6];
  const float* b_hh     = (const float*)d_in[7];
  const float* W1       = (const float*)d_in[8];
  const float* b1       = (const float*)d_in[9];
  const float* W2       = (const float*)d_in[10];
  const float* b2       = (const float*)d_in[11];
  float* outp = (float*)d_out;

  // workspace layout (bytes). embW2 region is reused post-LSTM for agg/out1/z.
  char* ws = (char*)d_ws;
  float* embW2   = (float*)(ws + 0);          // 32,768,000
  float* agg     = (float*)(ws + 0);          // alias, post-LSTM
  float* out1    = (float*)(ws + 5120000);    // alias
  float* z       = (float*)(ws + 25600000);   // alias
  float* h       = (float*)(ws + 32768000);   // 5,120,000
  int*   deg_out = (int*)(ws + 37888000);
  int*   deg_in  = (int*)(ws + 37968000);
  int*   cursor  = (int*)(ws + 38048000);
  int*   row_off = (int*)(ws + 38128000);
  float* n_src   = (float*)(ws + 38208016);
  float* n_dst   = (float*)(ws + 38288016);
  int*   csr     = (int*)(ws + 38368016);     // -> end 40,928,016

  hipMemsetAsync(ws + 37888000, 0, 240000, stream);

  // embW2 = perm(emb @ W_ih^T + b_ih + b_hh)   [32000 x 256]
  // (permutation applied on the B/bias load side; stores are linear)
  gemm_kernel<true, false, true, true><<<dim3(4, 500), 256, 0, stream>>>(
      emb, W_ih, b_ih, b_hh, embW2, VV, FH, IND);

  // MFMA LSTM (4-wave d-split) -> final hidden h [20000 x 64]
  lstm_mfma4_kernel<<<1250, 256, 0, stream>>>(features, embW2, W_hh, h);

  // graph degrees / CSR
  deg_kernel<<<2500, 256, 0, stream>>>(src, dst, deg_out, deg_in);
  scan_kernel<<<1, 1024, 0, stream>>>(deg_in, row_off);
  norm_kernel<<<79, 256, 0, stream>>>(deg_out, deg_in, n_src, n_dst);
  fill_kernel<<<2500, 256, 0, stream>>>(src, dst, row_off, cursor, csr);

  // conv1: aggregate then linear+relu
  agg1_kernel<<<5000, 256, 0, stream>>>(h, csr, row_off, n_src, n_dst, agg);
  gemm_kernel<false, true, false, false><<<dim3(4, 313), 256, 0, stream>>>(
      agg, W1, b1, nullptr, out1, NN, NHID, HH);

  // conv2: push W2 through the (linear) aggregation
  gemm16_kernel<<<1250, 256, 0, stream>>>(out1, W2, z);
  agg2_kernel<<<5000, 256, 0, stream>>>(z, csr, row_off, n_src, n_dst, b2, outp);
}

// Round 10
// 424.676 us; speedup vs baseline: 2.5715x; 1.0535x over previous
//
#include <hip/hip_runtime.h>
#include <cstdint>
#include <cstddef>

// Problem constants (match reference)
#define NN   20000   // nodes
#define LL   50      // seq len
#define IND  128     // input dim
#define HH   64      // hidden
#define FH   256     // 4*H
#define NHID 256     // hidden layer of conv1
#define NCLS 16      // classes
#define VV   32000   // vocab
#define EE   640000  // edges

typedef _Float16 f16x8 __attribute__((ext_vector_type(8)));
typedef _Float16 f16x4 __attribute__((ext_vector_type(4)));
typedef float    f32x4 __attribute__((ext_vector_type(4)));

// hardware v_rcp_f32 (~1 ulp): avoids the ~10-instr exact-division sequence
__device__ __forceinline__ float fast_rcp(float x) {
#if __has_builtin(__builtin_amdgcn_rcpf)
  return __builtin_amdgcn_rcpf(x);
#else
  return 1.0f / x;
#endif
}
__device__ __forceinline__ float sigmf(float x) {
  return fast_rcp(1.0f + __expf(-x));   // v_mul+v_exp+v_add+v_rcp
}
// overflow-safe tanh, rcp-based
__device__ __forceinline__ float tanhf_fast(float x) {
  float ax = fabsf(x);
  float t = __expf(-2.0f * ax);
  float r = (1.0f - t) * fast_rcp(1.0f + t);
  return copysignf(r, x);
}

// ---------------------------------------------------------------------------
// Generic tiled fp32 GEMM: C[M][Nc] = A[M][K] @ B (+bias1 [+bias2] [relu])
// B_IS_NK: B stored row-major [Nc][K] (C = A @ B^T); else B is [K][Nc].
// PERM (load-side): output column nn holds mathematical column
//   j(nn) = (nn&3)*64 + ((nn>>6)&3)*16 + ((nn>>2)&15)
// OUT_F16: store C as _Float16 (accumulation and bias adds remain fp32).
// ---------------------------------------------------------------------------
__device__ __forceinline__ int perm_inv(int nn) {
  return (nn & 3) * 64 + ((nn >> 6) & 3) * 16 + ((nn >> 2) & 15);
}

template <bool B_IS_NK, bool RELU, bool TWO_BIAS, bool PERM, bool OUT_F16>
__global__ __launch_bounds__(256) void gemm_kernel(
    const float* __restrict__ A, const float* __restrict__ B,
    const float* __restrict__ bias1, const float* __restrict__ bias2,
    float* __restrict__ C, int M, int Ncols, int K) {
  __shared__ float As[64 * 17];
  __shared__ float Bs[16 * 68];
  const int tid = threadIdx.x;
  const int tx = tid & 15, ty = tid >> 4;
  const int m0 = blockIdx.y * 64, n0 = blockIdx.x * 64;

  float acc[4][4];
#pragma unroll
  for (int i = 0; i < 4; ++i)
#pragma unroll
    for (int j = 0; j < 4; ++j) acc[i][j] = 0.0f;

  for (int k0 = 0; k0 < K; k0 += 16) {
    {
      int row = tid >> 2, c4 = tid & 3;
      float4 v = make_float4(0.f, 0.f, 0.f, 0.f);
      if (m0 + row < M)
        v = *(const float4*)(A + (size_t)(m0 + row) * K + k0 + c4 * 4);
      As[row * 17 + c4 * 4 + 0] = v.x;
      As[row * 17 + c4 * 4 + 1] = v.y;
      As[row * 17 + c4 * 4 + 2] = v.z;
      As[row * 17 + c4 * 4 + 3] = v.w;
    }
    if constexpr (B_IS_NK) {
      int n = tid >> 2, c4 = tid & 3;
      int gn = n0 + n;
      if constexpr (PERM) gn = perm_inv(gn);
      float4 v = *(const float4*)(B + (size_t)gn * K + k0 + c4 * 4);
      Bs[(c4 * 4 + 0) * 68 + n] = v.x;
      Bs[(c4 * 4 + 1) * 68 + n] = v.y;
      Bs[(c4 * 4 + 2) * 68 + n] = v.z;
      Bs[(c4 * 4 + 3) * 68 + n] = v.w;
    } else {
      int k = tid >> 4, n4 = tid & 15;
      float4 v = *(const float4*)(B + (size_t)(k0 + k) * Ncols + n0 + n4 * 4);
      *(float4*)(Bs + k * 68 + n4 * 4) = v;
    }
    __syncthreads();
#pragma unroll
    for (int k = 0; k < 16; ++k) {
      float4 bv = *(const float4*)(Bs + k * 68 + tx * 4);
      float a0 = As[(ty * 4 + 0) * 17 + k];
      float a1 = As[(ty * 4 + 1) * 17 + k];
      float a2 = As[(ty * 4 + 2) * 17 + k];
      float a3 = As[(ty * 4 + 3) * 17 + k];
      acc[0][0] += a0 * bv.x; acc[0][1] += a0 * bv.y; acc[0][2] += a0 * bv.z; acc[0][3] += a0 * bv.w;
      acc[1][0] += a1 * bv.x; acc[1][1] += a1 * bv.y; acc[1][2] += a1 * bv.z; acc[1][3] += a1 * bv.w;
      acc[2][0] += a2 * bv.x; acc[2][1] += a2 * bv.y; acc[2][2] += a2 * bv.z; acc[2][3] += a2 * bv.w;
      acc[3][0] += a3 * bv.x; acc[3][1] += a3 * bv.y; acc[3][2] += a3 * bv.z; acc[3][3] += a3 * bv.w;
    }
    __syncthreads();
  }
#pragma unroll
  for (int i = 0; i < 4; ++i) {
    int m = m0 + ty * 4 + i;
    if (m >= M) continue;
#pragma unroll
    for (int j = 0; j < 4; ++j) {
      int n = n0 + tx * 4 + j;
      int bn = PERM ? perm_inv(n) : n;
      float v = acc[i][j] + bias1[bn];
      if constexpr (TWO_BIAS) v += bias2[bn];
      if constexpr (RELU) v = fmaxf(v, 0.0f);
      if constexpr (OUT_F16)
        ((_Float16*)C)[(size_t)m * Ncols + n] = (_Float16)v;  // linear, coalesced
      else
        C[(size_t)m * Ncols + n] = v;   // linear, coalesced
    }
  }
}

// ---------------------------------------------------------------------------
// MFMA LSTM, 4-wave d-split: 1250 blocks x 256 threads (4 waves), 16 nodes
// per block, wave w owns d in [16w, 16w+16) for all 16 nodes.
// Per wave per step: 8 mfma_f32_16x16x32_f16 (4 gates x 2 k-halves), 4
// activation quads/thread (rcp-based, no fp32 div), 4 embW2h f16x4 gathers
// (8 B/lane, half the fetch of fp32) prefetched one full step ahead.
// h double-buffered in XOR-swizzled LDS; one barrier per step.
// D-layout: row=(lane>>4)*4+reg -> node, col=lane&15 -> d-within-tile.
// ---------------------------------------------------------------------------
__global__ __launch_bounds__(256) void lstm_mfma4_kernel(
    const int* __restrict__ feat, const _Float16* __restrict__ embW2h,
    const float* __restrict__ W_hh, float* __restrict__ h_out) {
  __shared__ __align__(16) _Float16 hbuf[2][16 * 64];
  __shared__ int fbuf[16 * LL];

  const int tid = threadIdx.x;
  const int l   = tid & 63;
  const int w   = tid >> 6;   // wave id = d-tile (0..3)
  const int cc  = l & 15;
  const int g4  = l >> 4;
  const int n0  = blockIdx.x * 16;

  // ---- B-frags for this wave's 4 gate col-tiles (cols g*64 + w*16 + cc)
  f16x8 Bf[4][2];
#pragma unroll
  for (int g = 0; g < 4; ++g)
#pragma unroll
    for (int kh = 0; kh < 2; ++kh) {
      const float* wp = W_hh + (g * 64 + w * 16 + cc) * 64 + kh * 32 + g4 * 8;
      float4 w0 = *(const float4*)(wp);
      float4 w1 = *(const float4*)(wp + 4);
      f16x8 b;
      b[0] = (_Float16)w0.x; b[1] = (_Float16)w0.y;
      b[2] = (_Float16)w0.z; b[3] = (_Float16)w0.w;
      b[4] = (_Float16)w1.x; b[5] = (_Float16)w1.y;
      b[6] = (_Float16)w1.z; b[7] = (_Float16)w1.w;
      Bf[g][kh] = b;
    }

  // ---- zero both h buffers (h(-1)=0), stage feature rows
  for (int i = tid; i < 2 * 16 * 64; i += 256) ((_Float16*)hbuf)[i] = (_Float16)0.0f;
  for (int i = tid; i < 16 * LL; i += 256) fbuf[i] = feat[n0 * LL + i];

  // ---- A-frag read offsets (swizzled, same layout as verified kernel)
  const int aoff = cc * 128;
  const int sb0  = ((g4    ) ^ (cc & 7)) << 4;
  const int sb1  = ((g4 + 4) ^ (cc & 7)) << 4;

  // ---- h write byte-offsets: n = g4*4+r, d = w*16+cc
  int wr_off[4];
#pragma unroll
  for (int r = 0; r < 4; ++r) {
    int n = g4 * 4 + r;
    int dgrp = w * 2 + (cc >> 3);
    wr_off[r] = n * 128 + ((dgrp ^ (n & 7)) << 4) + (cc & 7) * 2;
  }

  float c_reg[4];
#pragma unroll
  for (int r = 0; r < 4; ++r) c_reg[r] = 0.0f;

  __syncthreads();

  // ---- prologue: ew for t=0 (f16x4, 8 B per lane)
  f16x4 ewA[4];
#pragma unroll
  for (int r = 0; r < 4; ++r) {
    int row = fbuf[(g4 * 4 + r) * LL + 0];
    ewA[r] = *(const f16x4*)(embW2h + (size_t)row * FH + w * 64 + cc * 4);
  }

  for (int t = 0; t < LL; ++t) {
    const char* hbR = (const char*)hbuf[t & 1];        // h(t-1)
    _Float16*   hbW = hbuf[(t & 1) ^ 1];               // h(t)

    f16x8 A0 = *(const f16x8*)(hbR + aoff + sb0);
    f16x8 A1 = *(const f16x8*)(hbR + aoff + sb1);

    // issue next step's ew (full-step latency hiding)
    const int tn = (t < LL - 1) ? t + 1 : t;
    f16x4 ewN[4];
#pragma unroll
    for (int r = 0; r < 4; ++r) {
      int row = fbuf[(g4 * 4 + r) * LL + tn];
      ewN[r] = *(const f16x4*)(embW2h + (size_t)row * FH + w * 64 + cc * 4);
    }

    f32x4 z = {0.f, 0.f, 0.f, 0.f};
    f32x4 aci = __builtin_amdgcn_mfma_f32_16x16x32_f16(A0, Bf[0][0], z, 0, 0, 0);
    aci = __builtin_amdgcn_mfma_f32_16x16x32_f16(A1, Bf[0][1], aci, 0, 0, 0);
    f32x4 acf = __builtin_amdgcn_mfma_f32_16x16x32_f16(A0, Bf[1][0], z, 0, 0, 0);
    acf = __builtin_amdgcn_mfma_f32_16x16x32_f16(A1, Bf[1][1], acf, 0, 0, 0);
    f32x4 acg = __builtin_amdgcn_mfma_f32_16x16x32_f16(A0, Bf[2][0], z, 0, 0, 0);
    acg = __builtin_amdgcn_mfma_f32_16x16x32_f16(A1, Bf[2][1], acg, 0, 0, 0);
    f32x4 aco = __builtin_amdgcn_mfma_f32_16x16x32_f16(A0, Bf[3][0], z, 0, 0, 0);
    aco = __builtin_amdgcn_mfma_f32_16x16x32_f16(A1, Bf[3][1], aco, 0, 0, 0);

    // activation: acc component r -> node g4*4+r, at d = w*16+cc
#pragma unroll
    for (int r = 0; r < 4; ++r) {
      float gi = sigmf(aci[r] + (float)ewA[r][0]);
      float gf = sigmf(acf[r] + (float)ewA[r][1]);
      float gg = tanhf_fast(acg[r] + (float)ewA[r][2]);
      float go = sigmf(aco[r] + (float)ewA[r][3]);
      float cn = gf * c_reg[r] + gi * gg;
      c_reg[r] = cn;
      float hn = go * tanhf_fast(cn);
      *(_Float16*)((char*)hbW + wr_off[r]) = (_Float16)hn;
      if (t == LL - 1)
        h_out[(size_t)(n0 + g4 * 4 + r) * HH + w * 16 + cc] = hn;
      ewA[r] = ewN[r];
    }
    __syncthreads();  // h(t) complete before any wave reads it at t+1
  }
}

// ---------------------------------------------------------------------------
// Graph plumbing
// ---------------------------------------------------------------------------
__global__ __launch_bounds__(256) void deg_kernel(
    const int* __restrict__ src, const int* __restrict__ dst,
    int* __restrict__ deg_out, int* __restrict__ deg_in) {
  int i = blockIdx.x * 256 + threadIdx.x;
  if (i < EE) {
    atomicAdd(&deg_out[src[i]], 1);
    atomicAdd(&deg_in[dst[i]], 1);
  }
}

__global__ __launch_bounds__(1024) void scan_kernel(
    const int* __restrict__ deg_in, int* __restrict__ row_off) {
  __shared__ int partial[1024];
  const int tid = threadIdx.x;
  constexpr int CH = 20;
  int base = tid * CH;
  int local[CH];
  int s = 0;
#pragma unroll
  for (int i = 0; i < CH; ++i) {
    int v = (base + i < NN) ? deg_in[base + i] : 0;
    local[i] = s;
    s += v;
  }
  partial[tid] = s;
  __syncthreads();
  for (int off = 1; off < 1024; off <<= 1) {
    int v = (tid >= off) ? partial[tid - off] : 0;
    __syncthreads();
    partial[tid] += v;
    __syncthreads();
  }
  int pre = (tid > 0) ? partial[tid - 1] : 0;
#pragma unroll
  for (int i = 0; i < CH; ++i)
    if (base + i < NN) row_off[base + i] = pre + local[i];
  if (tid == 1023) row_off[NN] = partial[1023];
}

__global__ __launch_bounds__(256) void norm_kernel(
    const int* __restrict__ deg_out, const int* __restrict__ deg_in,
    float* __restrict__ n_src, float* __restrict__ n_dst) {
  int i = blockIdx.x * 256 + threadIdx.x;
  if (i >= NN) return;
  int dro = deg_out[i], dri = deg_in[i];
  n_src[i] = (dro > 0) ? rsqrtf((float)dro) : 1.0f;
  n_dst[i] = (dri > 0) ? rsqrtf((float)dri) : 1.0f;
}

__global__ __launch_bounds__(256) void fill_kernel(
    const int* __restrict__ src, const int* __restrict__ dst,
    const int* __restrict__ row_off, int* __restrict__ cursor,
    int* __restrict__ csr_src) {
  int i = blockIdx.x * 256 + threadIdx.x;
  if (i < EE) {
    int d = dst[i];
    int pos = atomicAdd(&cursor[d], 1);
    csr_src[row_off[d] + pos] = src[i];
  }
}

__global__ __launch_bounds__(256) void agg1_kernel(
    const float* __restrict__ h, const int* __restrict__ csr,
    const int* __restrict__ roff, const float* __restrict__ nsrc,
    const float* __restrict__ ndst, float* __restrict__ agg) {
  int node = blockIdx.x * 4 + (threadIdx.x >> 6);
  int lane = threadIdx.x & 63;
  if (node >= NN) return;
  int beg = roff[node], end = roff[node + 1];
  float a = 0.0f;
  int e = beg;
  for (; e + 4 <= end; e += 4) {
    int s0 = csr[e], s1 = csr[e + 1], s2 = csr[e + 2], s3 = csr[e + 3];
    float w0 = nsrc[s0], w1 = nsrc[s1], w2 = nsrc[s2], w3 = nsrc[s3];
    a += h[(size_t)s0 * HH + lane] * w0;
    a += h[(size_t)s1 * HH + lane] * w1;
    a += h[(size_t)s2 * HH + lane] * w2;
    a += h[(size_t)s3 * HH + lane] * w3;
  }
  for (; e < end; ++e) {
    int s = csr[e];
    a += h[(size_t)s * HH + lane] * nsrc[s];
  }
  agg[(size_t)node * HH + lane] = a * ndst[node];
}

__global__ __launch_bounds__(256) void gemm16_kernel(
    const float* __restrict__ A, const float* __restrict__ W2,
    float* __restrict__ z) {
  __shared__ float w[NHID * NCLS];
  for (int i = threadIdx.x; i < NHID * NCLS; i += 256) w[i] = W2[i];
  __syncthreads();
  int node = blockIdx.x * 16 + (threadIdx.x >> 4);
  int j = threadIdx.x & 15;
  if (node >= NN) return;
  const float* a = A + (size_t)node * NHID;
  float acc = 0.0f;
#pragma unroll 8
  for (int k = 0; k < NHID; k += 4) {
    float4 av = *(const float4*)(a + k);
    acc += av.x * w[(k + 0) * NCLS + j] + av.y * w[(k + 1) * NCLS + j] +
           av.z * w[(k + 2) * NCLS + j] + av.w * w[(k + 3) * NCLS + j];
  }
  z[(size_t)node * NCLS + j] = acc;
}

__global__ __launch_bounds__(256) void agg2_kernel(
    const float* __restrict__ z, const int* __restrict__ csr,
    const int* __restrict__ roff, const float* __restrict__ nsrc,
    const float* __restrict__ ndst, const float* __restrict__ b2,
    float* __restrict__ out) {
  int node = blockIdx.x * 4 + (threadIdx.x >> 6);
  int lane = threadIdx.x & 63;
  if (node >= NN) return;
  int dim = lane & 15, es = lane >> 4;
  int beg = roff[node], end = roff[node + 1];
  float a = 0.0f;
  for (int e = beg + es; e < end; e += 4) {
    int s = csr[e];
    a += z[(size_t)s * NCLS + dim] * nsrc[s];
  }
  a += __shfl_xor(a, 16, 64);
  a += __shfl_xor(a, 32, 64);
  if (lane < 16) out[(size_t)node * NCLS + dim] = ndst[node] * a + b2[dim];
}

// ---------------------------------------------------------------------------
extern "C" void kernel_launch(void* const* d_in, const int* in_sizes, int n_in,
                              void* d_out, int out_size, void* d_ws,
                              size_t ws_size, hipStream_t stream) {
  const int*   features = (const int*)d_in[0];
  const int*   src      = (const int*)d_in[1];
  const int*   dst      = (const int*)d_in[2];
  const float* emb      = (const float*)d_in[3];
  const float* W_ih     = (const float*)d_in[4];
  const float* W_hh     = (const float*)d_in[5];
  const float* b_ih     = (const float*)d_in[6];
  const float* b_hh     = (const float*)d_in[7];
  const float* W1       = (const float*)d_in[8];
  const float* b1       = (const float*)d_in[9];
  const float* W2       = (const float*)d_in[10];
  const float* b2       = (const float*)d_in[11];
  float* outp = (float*)d_out;

  // workspace layout (bytes). embW2h (fp16, 16.4 MB) is reused post-LSTM.
  char* ws = (char*)d_ws;
  _Float16* embW2h = (_Float16*)(ws + 0);     // 16,384,000
  float* agg     = (float*)(ws + 0);          // alias, post-LSTM
  float* out1    = (float*)(ws + 5120000);    // alias
  float* z       = (float*)(ws + 25600000);   // alias
  float* h       = (float*)(ws + 32768000);   // 5,120,000
  int*   deg_out = (int*)(ws + 37888000);
  int*   deg_in  = (int*)(ws + 37968000);
  int*   cursor  = (int*)(ws + 38048000);
  int*   row_off = (int*)(ws + 38128000);
  float* n_src   = (float*)(ws + 38208016);
  float* n_dst   = (float*)(ws + 38288016);
  int*   csr     = (int*)(ws + 38368016);     // -> end 40,928,016

  hipMemsetAsync(ws + 37888000, 0, 240000, stream);

  // embW2h = perm(emb @ W_ih^T + b_ih + b_hh) as fp16   [32000 x 256]
  // (permutation applied on the B/bias load side; stores are linear fp16)
  gemm_kernel<true, false, true, true, true><<<dim3(4, 500), 256, 0, stream>>>(
      emb, W_ih, b_ih, b_hh, (float*)embW2h, VV, FH, IND);

  // MFMA LSTM (4-wave d-split, fp16 embW gather) -> final hidden h [20000 x 64]
  lstm_mfma4_kernel<<<1250, 256, 0, stream>>>(features, embW2h, W_hh, h);

  // graph degrees / CSR
  deg_kernel<<<2500, 256, 0, stream>>>(src, dst, deg_out, deg_in);
  scan_kernel<<<1, 1024, 0, stream>>>(deg_in, row_off);
  norm_kernel<<<79, 256, 0, stream>>>(deg_out, deg_in, n_src, n_dst);
  fill_kernel<<<2500, 256, 0, stream>>>(src, dst, row_off, cursor, csr);

  // conv1: aggregate then linear+relu
  agg1_kernel<<<5000, 256, 0, stream>>>(h, csr, row_off, n_src, n_dst, agg);
  gemm_kernel<false, true, false, false, false><<<dim3(4, 313), 256, 0, stream>>>(
      agg, W1, b1, nullptr, out1, NN, NHID, HH);

  // conv2: push W2 through the (linear) aggregation
  gemm16_kernel<<<1250, 256, 0, stream>>>(out1, W2, z);
  agg2_kernel<<<5000, 256, 0, stream>>>(z, csr, row_off, n_src, n_dst, b2, outp);
}

// Round 11
// 412.447 us; speedup vs baseline: 2.6478x; 1.0296x over previous
//
#include <hip/hip_runtime.h>
#include <cstdint>
#include <cstddef>

// Problem constants (match reference)
#define NN   20000   // nodes
#define LL   50      // seq len
#define IND  128     // input dim
#define HH   64      // hidden
#define FH   256     // 4*H
#define NHID 256     // hidden layer of conv1
#define NCLS 16      // classes
#define VV   32000   // vocab
#define EE   640000  // edges

typedef _Float16 f16x8 __attribute__((ext_vector_type(8)));
typedef _Float16 f16x4 __attribute__((ext_vector_type(4)));
typedef float    f32x4 __attribute__((ext_vector_type(4)));

// hardware v_rcp_f32 (~1 ulp): avoids the ~10-instr exact-division sequence
__device__ __forceinline__ float fast_rcp(float x) {
#if __has_builtin(__builtin_amdgcn_rcpf)
  return __builtin_amdgcn_rcpf(x);
#else
  return 1.0f / x;
#endif
}
__device__ __forceinline__ float sigmf(float x) {
  return fast_rcp(1.0f + __expf(-x));   // v_mul+v_exp+v_add+v_rcp
}
// overflow-safe tanh, rcp-based
__device__ __forceinline__ float tanhf_fast(float x) {
  float ax = fabsf(x);
  float t = __expf(-2.0f * ax);
  float r = (1.0f - t) * fast_rcp(1.0f + t);
  return copysignf(r, x);
}

// ---------------------------------------------------------------------------
// Generic tiled fp32 GEMM: C[M][Nc] = A[M][K] @ B (+bias1 [+bias2] [relu])
// B_IS_NK: B stored row-major [Nc][K] (C = A @ B^T); else B is [K][Nc].
// PERM (load-side): output column nn holds mathematical column
//   j(nn) = (nn&3)*64 + ((nn>>6)&3)*16 + ((nn>>2)&15)
// OUT_F16: store C as _Float16 (accumulation and bias adds remain fp32).
// ---------------------------------------------------------------------------
__device__ __forceinline__ int perm_inv(int nn) {
  return (nn & 3) * 64 + ((nn >> 6) & 3) * 16 + ((nn >> 2) & 15);
}

template <bool B_IS_NK, bool RELU, bool TWO_BIAS, bool PERM, bool OUT_F16>
__global__ __launch_bounds__(256) void gemm_kernel(
    const float* __restrict__ A, const float* __restrict__ B,
    const float* __restrict__ bias1, const float* __restrict__ bias2,
    float* __restrict__ C, int M, int Ncols, int K) {
  __shared__ float As[64 * 17];
  __shared__ float Bs[16 * 68];
  const int tid = threadIdx.x;
  const int tx = tid & 15, ty = tid >> 4;
  const int m0 = blockIdx.y * 64, n0 = blockIdx.x * 64;

  float acc[4][4];
#pragma unroll
  for (int i = 0; i < 4; ++i)
#pragma unroll
    for (int j = 0; j < 4; ++j) acc[i][j] = 0.0f;

  for (int k0 = 0; k0 < K; k0 += 16) {
    {
      int row = tid >> 2, c4 = tid & 3;
      float4 v = make_float4(0.f, 0.f, 0.f, 0.f);
      if (m0 + row < M)
        v = *(const float4*)(A + (size_t)(m0 + row) * K + k0 + c4 * 4);
      As[row * 17 + c4 * 4 + 0] = v.x;
      As[row * 17 + c4 * 4 + 1] = v.y;
      As[row * 17 + c4 * 4 + 2] = v.z;
      As[row * 17 + c4 * 4 + 3] = v.w;
    }
    if constexpr (B_IS_NK) {
      int n = tid >> 2, c4 = tid & 3;
      int gn = n0 + n;
      if constexpr (PERM) gn = perm_inv(gn);
      float4 v = *(const float4*)(B + (size_t)gn * K + k0 + c4 * 4);
      Bs[(c4 * 4 + 0) * 68 + n] = v.x;
      Bs[(c4 * 4 + 1) * 68 + n] = v.y;
      Bs[(c4 * 4 + 2) * 68 + n] = v.z;
      Bs[(c4 * 4 + 3) * 68 + n] = v.w;
    } else {
      int k = tid >> 4, n4 = tid & 15;
      float4 v = *(const float4*)(B + (size_t)(k0 + k) * Ncols + n0 + n4 * 4);
      *(float4*)(Bs + k * 68 + n4 * 4) = v;
    }
    __syncthreads();
#pragma unroll
    for (int k = 0; k < 16; ++k) {
      float4 bv = *(const float4*)(Bs + k * 68 + tx * 4);
      float a0 = As[(ty * 4 + 0) * 17 + k];
      float a1 = As[(ty * 4 + 1) * 17 + k];
      float a2 = As[(ty * 4 + 2) * 17 + k];
      float a3 = As[(ty * 4 + 3) * 17 + k];
      acc[0][0] += a0 * bv.x; acc[0][1] += a0 * bv.y; acc[0][2] += a0 * bv.z; acc[0][3] += a0 * bv.w;
      acc[1][0] += a1 * bv.x; acc[1][1] += a1 * bv.y; acc[1][2] += a1 * bv.z; acc[1][3] += a1 * bv.w;
      acc[2][0] += a2 * bv.x; acc[2][1] += a2 * bv.y; acc[2][2] += a2 * bv.z; acc[2][3] += a2 * bv.w;
      acc[3][0] += a3 * bv.x; acc[3][1] += a3 * bv.y; acc[3][2] += a3 * bv.z; acc[3][3] += a3 * bv.w;
    }
    __syncthreads();
  }
#pragma unroll
  for (int i = 0; i < 4; ++i) {
    int m = m0 + ty * 4 + i;
    if (m >= M) continue;
#pragma unroll
    for (int j = 0; j < 4; ++j) {
      int n = n0 + tx * 4 + j;
      int bn = PERM ? perm_inv(n) : n;
      float v = acc[i][j] + bias1[bn];
      if constexpr (TWO_BIAS) v += bias2[bn];
      if constexpr (RELU) v = fmaxf(v, 0.0f);
      if constexpr (OUT_F16)
        ((_Float16*)C)[(size_t)m * Ncols + n] = (_Float16)v;  // linear, coalesced
      else
        C[(size_t)m * Ncols + n] = v;   // linear, coalesced
    }
  }
}

// ---------------------------------------------------------------------------
// MFMA LSTM, 4-wave d-split: 1250 blocks x 256 threads (4 waves), 16 nodes
// per block, wave w owns d in [16w, 16w+16) for all 16 nodes.
// Per wave per step: 8 mfma_f32_16x16x32_f16 (4 gates x 2 k-halves), 4
// activation quads/thread (rcp-based, no fp32 div), 4 embW2h f16x4 gathers
// (8 B/lane) prefetched one full step ahead. h double-buffered in
// XOR-swizzled LDS; one barrier per step. h_out stored as fp16 (the exact
// values the recurrence used internally) -> 2.56 MB, per-XCD-L2-resident
// for the conv1 gather.
// ---------------------------------------------------------------------------
__global__ __launch_bounds__(256) void lstm_mfma4_kernel(
    const int* __restrict__ feat, const _Float16* __restrict__ embW2h,
    const float* __restrict__ W_hh, _Float16* __restrict__ h_out) {
  __shared__ __align__(16) _Float16 hbuf[2][16 * 64];
  __shared__ int fbuf[16 * LL];

  const int tid = threadIdx.x;
  const int l   = tid & 63;
  const int w   = tid >> 6;   // wave id = d-tile (0..3)
  const int cc  = l & 15;
  const int g4  = l >> 4;
  const int n0  = blockIdx.x * 16;

  // ---- B-frags for this wave's 4 gate col-tiles (cols g*64 + w*16 + cc)
  f16x8 Bf[4][2];
#pragma unroll
  for (int g = 0; g < 4; ++g)
#pragma unroll
    for (int kh = 0; kh < 2; ++kh) {
      const float* wp = W_hh + (g * 64 + w * 16 + cc) * 64 + kh * 32 + g4 * 8;
      float4 w0 = *(const float4*)(wp);
      float4 w1 = *(const float4*)(wp + 4);
      f16x8 b;
      b[0] = (_Float16)w0.x; b[1] = (_Float16)w0.y;
      b[2] = (_Float16)w0.z; b[3] = (_Float16)w0.w;
      b[4] = (_Float16)w1.x; b[5] = (_Float16)w1.y;
      b[6] = (_Float16)w1.z; b[7] = (_Float16)w1.w;
      Bf[g][kh] = b;
    }

  // ---- zero both h buffers (h(-1)=0), stage feature rows
  for (int i = tid; i < 2 * 16 * 64; i += 256) ((_Float16*)hbuf)[i] = (_Float16)0.0f;
  for (int i = tid; i < 16 * LL; i += 256) fbuf[i] = feat[n0 * LL + i];

  // ---- A-frag read offsets (swizzled, same layout as verified kernel)
  const int aoff = cc * 128;
  const int sb0  = ((g4    ) ^ (cc & 7)) << 4;
  const int sb1  = ((g4 + 4) ^ (cc & 7)) << 4;

  // ---- h write byte-offsets: n = g4*4+r, d = w*16+cc
  int wr_off[4];
#pragma unroll
  for (int r = 0; r < 4; ++r) {
    int n = g4 * 4 + r;
    int dgrp = w * 2 + (cc >> 3);
    wr_off[r] = n * 128 + ((dgrp ^ (n & 7)) << 4) + (cc & 7) * 2;
  }

  float c_reg[4];
#pragma unroll
  for (int r = 0; r < 4; ++r) c_reg[r] = 0.0f;

  __syncthreads();

  // ---- prologue: ew for t=0 (f16x4, 8 B per lane)
  f16x4 ewA[4];
#pragma unroll
  for (int r = 0; r < 4; ++r) {
    int row = fbuf[(g4 * 4 + r) * LL + 0];
    ewA[r] = *(const f16x4*)(embW2h + (size_t)row * FH + w * 64 + cc * 4);
  }

  for (int t = 0; t < LL; ++t) {
    const char* hbR = (const char*)hbuf[t & 1];        // h(t-1)
    _Float16*   hbW = hbuf[(t & 1) ^ 1];               // h(t)

    f16x8 A0 = *(const f16x8*)(hbR + aoff + sb0);
    f16x8 A1 = *(const f16x8*)(hbR + aoff + sb1);

    // issue next step's ew (full-step latency hiding)
    const int tn = (t < LL - 1) ? t + 1 : t;
    f16x4 ewN[4];
#pragma unroll
    for (int r = 0; r < 4; ++r) {
      int row = fbuf[(g4 * 4 + r) * LL + tn];
      ewN[r] = *(const f16x4*)(embW2h + (size_t)row * FH + w * 64 + cc * 4);
    }

    f32x4 z = {0.f, 0.f, 0.f, 0.f};
    f32x4 aci = __builtin_amdgcn_mfma_f32_16x16x32_f16(A0, Bf[0][0], z, 0, 0, 0);
    aci = __builtin_amdgcn_mfma_f32_16x16x32_f16(A1, Bf[0][1], aci, 0, 0, 0);
    f32x4 acf = __builtin_amdgcn_mfma_f32_16x16x32_f16(A0, Bf[1][0], z, 0, 0, 0);
    acf = __builtin_amdgcn_mfma_f32_16x16x32_f16(A1, Bf[1][1], acf, 0, 0, 0);
    f32x4 acg = __builtin_amdgcn_mfma_f32_16x16x32_f16(A0, Bf[2][0], z, 0, 0, 0);
    acg = __builtin_amdgcn_mfma_f32_16x16x32_f16(A1, Bf[2][1], acg, 0, 0, 0);
    f32x4 aco = __builtin_amdgcn_mfma_f32_16x16x32_f16(A0, Bf[3][0], z, 0, 0, 0);
    aco = __builtin_amdgcn_mfma_f32_16x16x32_f16(A1, Bf[3][1], aco, 0, 0, 0);

    // activation: acc component r -> node g4*4+r, at d = w*16+cc
#pragma unroll
    for (int r = 0; r < 4; ++r) {
      float gi = sigmf(aci[r] + (float)ewA[r][0]);
      float gf = sigmf(acf[r] + (float)ewA[r][1]);
      float gg = tanhf_fast(acg[r] + (float)ewA[r][2]);
      float go = sigmf(aco[r] + (float)ewA[r][3]);
      float cn = gf * c_reg[r] + gi * gg;
      c_reg[r] = cn;
      float hn = go * tanhf_fast(cn);
      _Float16 hq = (_Float16)hn;
      *(_Float16*)((char*)hbW + wr_off[r]) = hq;
      if (t == LL - 1)
        h_out[(size_t)(n0 + g4 * 4 + r) * HH + w * 16 + cc] = hq;
      ewA[r] = ewN[r];
    }
    __syncthreads();  // h(t) complete before any wave reads it at t+1
  }
}

// ---------------------------------------------------------------------------
// Graph plumbing
// ---------------------------------------------------------------------------
__global__ __launch_bounds__(256) void deg_kernel(
    const int* __restrict__ src, const int* __restrict__ dst,
    int* __restrict__ deg_out, int* __restrict__ deg_in) {
  int i = blockIdx.x * 256 + threadIdx.x;
  if (i < EE) {
    atomicAdd(&deg_out[src[i]], 1);
    atomicAdd(&deg_in[dst[i]], 1);
  }
}

__global__ __launch_bounds__(1024) void scan_kernel(
    const int* __restrict__ deg_in, int* __restrict__ row_off) {
  __shared__ int partial[1024];
  const int tid = threadIdx.x;
  constexpr int CH = 20;
  int base = tid * CH;
  int local[CH];
  int s = 0;
#pragma unroll
  for (int i = 0; i < CH; ++i) {
    int v = (base + i < NN) ? deg_in[base + i] : 0;
    local[i] = s;
    s += v;
  }
  partial[tid] = s;
  __syncthreads();
  for (int off = 1; off < 1024; off <<= 1) {
    int v = (tid >= off) ? partial[tid - off] : 0;
    __syncthreads();
    partial[tid] += v;
    __syncthreads();
  }
  int pre = (tid > 0) ? partial[tid - 1] : 0;
#pragma unroll
  for (int i = 0; i < CH; ++i)
    if (base + i < NN) row_off[base + i] = pre + local[i];
  if (tid == 1023) row_off[NN] = partial[1023];
}

__global__ __launch_bounds__(256) void norm_kernel(
    const int* __restrict__ deg_out, const int* __restrict__ deg_in,
    float* __restrict__ n_src, float* __restrict__ n_dst) {
  int i = blockIdx.x * 256 + threadIdx.x;
  if (i >= NN) return;
  int dro = deg_out[i], dri = deg_in[i];
  n_src[i] = (dro > 0) ? rsqrtf((float)dro) : 1.0f;
  n_dst[i] = (dri > 0) ? rsqrtf((float)dri) : 1.0f;
}

__global__ __launch_bounds__(256) void fill_kernel(
    const int* __restrict__ src, const int* __restrict__ dst,
    const int* __restrict__ row_off, int* __restrict__ cursor,
    int* __restrict__ csr_src) {
  int i = blockIdx.x * 256 + threadIdx.x;
  if (i < EE) {
    int d = dst[i];
    int pos = atomicAdd(&cursor[d], 1);
    csr_src[row_off[d] + pos] = src[i];
  }
}

__global__ __launch_bounds__(256) void agg1_kernel(
    const _Float16* __restrict__ h, const int* __restrict__ csr,
    const int* __restrict__ roff, const float* __restrict__ nsrc,
    const float* __restrict__ ndst, float* __restrict__ agg) {
  int node = blockIdx.x * 4 + (threadIdx.x >> 6);
  int lane = threadIdx.x & 63;
  if (node >= NN) return;
  int beg = roff[node], end = roff[node + 1];
  float a = 0.0f;
  int e = beg;
  for (; e + 4 <= end; e += 4) {
    int s0 = csr[e], s1 = csr[e + 1], s2 = csr[e + 2], s3 = csr[e + 3];
    float w0 = nsrc[s0], w1 = nsrc[s1], w2 = nsrc[s2], w3 = nsrc[s3];
    a += (float)h[(size_t)s0 * HH + lane] * w0;
    a += (float)h[(size_t)s1 * HH + lane] * w1;
    a += (float)h[(size_t)s2 * HH + lane] * w2;
    a += (float)h[(size_t)s3 * HH + lane] * w3;
  }
  for (; e < end; ++e) {
    int s = csr[e];
    a += (float)h[(size_t)s * HH + lane] * nsrc[s];
  }
  agg[(size_t)node * HH + lane] = a * ndst[node];
}

__global__ __launch_bounds__(256) void gemm16_kernel(
    const float* __restrict__ A, const float* __restrict__ W2,
    float* __restrict__ z) {
  __shared__ float w[NHID * NCLS];
  for (int i = threadIdx.x; i < NHID * NCLS; i += 256) w[i] = W2[i];
  __syncthreads();
  int node = blockIdx.x * 16 + (threadIdx.x >> 4);
  int j = threadIdx.x & 15;
  if (node >= NN) return;
  const float* a = A + (size_t)node * NHID;
  float acc = 0.0f;
#pragma unroll 8
  for (int k = 0; k < NHID; k += 4) {
    float4 av = *(const float4*)(a + k);
    acc += av.x * w[(k + 0) * NCLS + j] + av.y * w[(k + 1) * NCLS + j] +
           av.z * w[(k + 2) * NCLS + j] + av.w * w[(k + 3) * NCLS + j];
  }
  z[(size_t)node * NCLS + j] = acc;
}

__global__ __launch_bounds__(256) void agg2_kernel(
    const float* __restrict__ z, const int* __restrict__ csr,
    const int* __restrict__ roff, const float* __restrict__ nsrc,
    const float* __restrict__ ndst, const float* __restrict__ b2,
    float* __restrict__ out) {
  int node = blockIdx.x * 4 + (threadIdx.x >> 6);
  int lane = threadIdx.x & 63;
  if (node >= NN) return;
  int dim = lane & 15, es = lane >> 4;
  int beg = roff[node], end = roff[node + 1];
  float a = 0.0f;
  for (int e = beg + es; e < end; e += 4) {
    int s = csr[e];
    a += z[(size_t)s * NCLS + dim] * nsrc[s];
  }
  a += __shfl_xor(a, 16, 64);
  a += __shfl_xor(a, 32, 64);
  if (lane < 16) out[(size_t)node * NCLS + dim] = ndst[node] * a + b2[dim];
}

// ---------------------------------------------------------------------------
extern "C" void kernel_launch(void* const* d_in, const int* in_sizes, int n_in,
                              void* d_out, int out_size, void* d_ws,
                              size_t ws_size, hipStream_t stream) {
  const int*   features = (const int*)d_in[0];
  const int*   src      = (const int*)d_in[1];
  const int*   dst      = (const int*)d_in[2];
  const float* emb      = (const float*)d_in[3];
  const float* W_ih     = (const float*)d_in[4];
  const float* W_hh     = (const float*)d_in[5];
  const float* b_ih     = (const float*)d_in[6];
  const float* b_hh     = (const float*)d_in[7];
  const float* W1       = (const float*)d_in[8];
  const float* b1       = (const float*)d_in[9];
  const float* W2       = (const float*)d_in[10];
  const float* b2       = (const float*)d_in[11];
  float* outp = (float*)d_out;

  // workspace layout (bytes). embW2h (fp16, 16.4 MB) is reused post-LSTM.
  char* ws = (char*)d_ws;
  _Float16* embW2h = (_Float16*)(ws + 0);     // 16,384,000
  float* agg     = (float*)(ws + 0);          // alias, post-LSTM
  float* out1    = (float*)(ws + 5120000);    // alias
  float* z       = (float*)(ws + 25600000);   // alias
  _Float16* h    = (_Float16*)(ws + 32768000);// 2,560,000 (fp16)
  int*   deg_out = (int*)(ws + 37888000);
  int*   deg_in  = (int*)(ws + 37968000);
  int*   cursor  = (int*)(ws + 38048000);
  int*   row_off = (int*)(ws + 38128000);
  float* n_src   = (float*)(ws + 38208016);
  float* n_dst   = (float*)(ws + 38288016);
  int*   csr     = (int*)(ws + 38368016);     // -> end 40,928,016

  hipMemsetAsync(ws + 37888000, 0, 240000, stream);

  // embW2h = perm(emb @ W_ih^T + b_ih + b_hh) as fp16   [32000 x 256]
  gemm_kernel<true, false, true, true, true><<<dim3(4, 500), 256, 0, stream>>>(
      emb, W_ih, b_ih, b_hh, (float*)embW2h, VV, FH, IND);

  // MFMA LSTM (4-wave d-split, fp16 embW gather) -> final hidden h [20000 x 64] fp16
  lstm_mfma4_kernel<<<1250, 256, 0, stream>>>(features, embW2h, W_hh, h);

  // graph degrees / CSR
  deg_kernel<<<2500, 256, 0, stream>>>(src, dst, deg_out, deg_in);
  scan_kernel<<<1, 1024, 0, stream>>>(deg_in, row_off);
  norm_kernel<<<79, 256, 0, stream>>>(deg_out, deg_in, n_src, n_dst);
  fill_kernel<<<2500, 256, 0, stream>>>(src, dst, row_off, cursor, csr);

  // conv1: aggregate (fp16 h gather, L2-resident) then linear+relu
  agg1_kernel<<<5000, 256, 0, stream>>>(h, csr, row_off, n_src, n_dst, agg);
  gemm_kernel<false, true, false, false, false><<<dim3(4, 313), 256, 0, stream>>>(
      agg, W1, b1, nullptr, out1, NN, NHID, HH);

  // conv2: push W2 through the (linear) aggregation
  gemm16_kernel<<<1250, 256, 0, stream>>>(out1, W2, z);
  agg2_kernel<<<5000, 256, 0, stream>>>(z, csr, row_off, n_src, n_dst, b2, outp);
}